// Round 10
// baseline (822.515 us; speedup 1.0000x reference)
//
#include <hip/hip_runtime.h>
#include <hip/hip_bf16.h>

typedef __attribute__((ext_vector_type(8))) __bf16 bf16x8;
typedef __attribute__((ext_vector_type(4))) float f32x4;
typedef __attribute__((ext_vector_type(16))) float f32x16;
typedef __attribute__((ext_vector_type(8))) unsigned short u16x8;
typedef unsigned short u16;

#define DEVINL static __device__ __forceinline__

namespace {
constexpr int kB = 4;
constexpr int kS = 2048;
constexpr int kDM = 2048;
constexpr int kH = 16;
constexpr int kDK = 128;
constexpr int kM = kB * kS;        // 8192
constexpr int kNQKV = 3 * kDM;     // 6144
constexpr float kE2 = 0.08838834764831845f * 1.44269504088896f; // scale*log2(e)
}

DEVINL u16 f2bf(float f) {
  __hip_bfloat16 h = __float2bfloat16(f);
  return __builtin_bit_cast(u16, h);
}

#if __has_builtin(__builtin_amdgcn_exp2f)
DEVINL float exp2_fast(float x) { return __builtin_amdgcn_exp2f(x); }
#else
DEVINL float exp2_fast(float x) { return exp2f(x); }
#endif

#define GLOAD16(gp, lp) \
  __builtin_amdgcn_global_load_lds((const __attribute__((address_space(1))) void*)(gp), \
                                   (__attribute__((address_space(3))) void*)(lp), 16, 0, 0)

DEVINL bf16x8 lds_frag(const u16* p) { return *reinterpret_cast<const bf16x8*>(p); }

DEVINL f32x4 MFMA16x16(bf16x8 a, bf16x8 b, f32x4 c) {
  return __builtin_amdgcn_mfma_f32_16x16x32_bf16(a, b, c, 0, 0, 0);
}

struct TrueT { static constexpr bool value = true; };
struct FalseT { static constexpr bool value = false; };

// ---------------- cast x: fp32 -> bf16, x4 vectorized ----------------
__global__ __launch_bounds__(256) void cast_x_kernel(const float* __restrict__ x,
                                                     u16* __restrict__ o, int n4) {
  int i = blockIdx.x * 256 + threadIdx.x;
  if (i >= n4) return;
  float4 v = reinterpret_cast<const float4*>(x)[i];
  ushort4 r;
  r.x = f2bf(v.x); r.y = f2bf(v.y); r.z = f2bf(v.z); r.w = f2bf(v.w);
  reinterpret_cast<ushort4*>(o)[i] = r;
}

// ------------- transpose + cast weights: w[k][n] fp32 -> wt[n][k] bf16 -------------
__global__ __launch_bounds__(256) void transpose_w_kernel(const float* __restrict__ w0,
    const float* __restrict__ w1, const float* __restrict__ w2, const float* __restrict__ w3,
    u16* __restrict__ wtcat, u16* __restrict__ wot) {
  const float* src = (blockIdx.z == 0) ? w0 : (blockIdx.z == 1) ? w1
                    : (blockIdx.z == 2) ? w2 : w3;
  u16* dst = (blockIdx.z < 3) ? (wtcat + (size_t)blockIdx.z * kDM * kDM) : wot;
  __shared__ float tile[32][33];
  int n0 = blockIdx.x * 32, k0 = blockIdx.y * 32;
  int tx = threadIdx.x, ty = threadIdx.y;
#pragma unroll
  for (int i = 0; i < 4; ++i)
    tile[ty + i * 8][tx] = src[(size_t)(k0 + ty + i * 8) * kDM + n0 + tx];
  __syncthreads();
#pragma unroll
  for (int i = 0; i < 4; ++i)
    dst[(size_t)(n0 + ty + i * 8) * kDM + k0 + tx] = f2bf(tile[tx][ty + i * 8]);
}

// ===================== 256x256 8-phase GEMM (Bt layout), 16x16x32 MFMA ======
// Single barrier per phase (R9). Stage slotting R5; gates vmcnt(4) at P3/P7.
DEVINL void cstore(float* p, float v) { *p = v; }
DEVINL void cstore(u16* p, float v) { *p = f2bf(v); }

#define PH_BEGIN()                                     \
  __builtin_amdgcn_sched_barrier(0);                   \
  __builtin_amdgcn_s_barrier();                        \
  asm volatile("s_waitcnt lgkmcnt(0)" ::: "memory");   \
  __builtin_amdgcn_sched_barrier(0);                   \
  __builtin_amdgcn_s_setprio(1)

#define PH_END()                                       \
  __builtin_amdgcn_s_setprio(0);                       \
  __builtin_amdgcn_sched_barrier(0)

#define GATE4() \
  asm volatile("s_waitcnt vmcnt(4)" ::: "memory");     \
  __builtin_amdgcn_sched_barrier(0)

#define GATE0() \
  asm volatile("s_waitcnt vmcnt(0)" ::: "memory");     \
  __builtin_amdgcn_sched_barrier(0)

// read A-half MQ of tile buffer SB into DST[0..7]
#define RD_A(SB, MQ, DST)                                             \
  do {                                                                \
    _Pragma("unroll") for (int mf = 0; mf < 4; ++mf) {                \
      const u16* p_ = (SB) + (awrow + (MQ) * 64 + mf * 16) * 64;      \
      DST[mf * 2 + 0] = lds_frag(p_ + g0);                            \
      DST[mf * 2 + 1] = lds_frag(p_ + g1);                            \
    }                                                                 \
  } while (0)

// read B-half NH of tile buffer SB into b[NH*4 .. NH*4+3]
#define RD_BH(SB, NH)                                                 \
  do {                                                                \
    _Pragma("unroll") for (int nf = 0; nf < 2; ++nf) {                \
      const u16* p_ = (SB) + (bwrow + (NH) * 32 + nf * 16) * 64;      \
      b[(NH) * 4 + nf * 2 + 0] = lds_frag(p_ + g0);                   \
      b[(NH) * 4 + nf * 2 + 1] = lds_frag(p_ + g1);                   \
    }                                                                 \
  } while (0)

#define MMQ(MQ, NH, AF)                                               \
  do {                                                                \
    _Pragma("unroll") for (int mf = 0; mf < 4; ++mf)                  \
      _Pragma("unroll") for (int nf = 0; nf < 2; ++nf) {              \
        f32x4 t_ = acc[(MQ) * 4 + mf][(NH) * 2 + nf];                 \
        t_ = MFMA16x16(AF[mf * 2 + 0], b[(NH) * 4 + nf * 2 + 0], t_); \
        t_ = MFMA16x16(AF[mf * 2 + 1], b[(NH) * 4 + nf * 2 + 1], t_); \
        acc[(MQ) * 4 + mf][(NH) * 2 + nf] = t_;                       \
      }                                                               \
  } while (0)

#define STG_A(buf, R0, kt) \
  GLOAD16(baseA + (size_t)(R0) * lda + (size_t)(kt) * 64, ldsA + (buf) * 16384 + (R0) * 64)
#define STG_B(buf, R0, kt) \
  GLOAD16(baseB + (size_t)(R0) * ldb + (size_t)(kt) * 64, ldsB + (buf) * 16384 + (R0) * 64)

template <typename CT, bool WRITEV>
__global__ __launch_bounds__(512, 2) void gemm256_kernel(const u16* __restrict__ A,
    const u16* __restrict__ Bt, CT* __restrict__ C, u16* __restrict__ Vt,
    int K, int lda, int ldb, int ldc) {
  __shared__ __align__(16) u16 sA[2][16384];
  __shared__ __align__(16) u16 sB[2][16384];
  const int tid = threadIdx.x;
  const int lane = tid & 63, wid = tid >> 6;
  const int r15 = lane & 15, hi = lane >> 4;
  const int wm = wid >> 2, wn = wid & 3;

  // XCD-aware bijective swizzle (nwg % 8 == 0 for both launches)
  const int gx = gridDim.x, nwg = gx * gridDim.y;
  const int orig = blockIdx.y * gx + blockIdx.x;
  const int wg = (orig & 7) * (nwg >> 3) + (orig >> 3);
  const int n0 = (wg % gx) * 256;
  const int m0 = (wg / gx) * 256;

  const int NT = K >> 6;       // 64-wide k tiles (even)
  const int NITER = NT >> 1;

  // staging: thread stages 1 granule (16B) per 64-row chunk
  const int rc = tid >> 3;                         // row within chunk
  const int cg = (tid & 7) ^ (rc & 7);             // logical source granule
  const u16* baseA = A + (size_t)(m0 + rc) * lda + cg * 8;
  const u16* baseB = Bt + (size_t)(n0 + rc) * ldb + cg * 8;
  u16* ldsA = &sA[0][0] + rc * 64 + (tid & 7) * 8; // linear physical dest
  u16* ldsB = &sB[0][0] + rc * 64 + (tid & 7) * 8;

  // per-thread-constant read swizzle: row&7 == r15&7 for all fragment rows
  const int sw = r15 & 7;
  const int g0 = (hi ^ sw) * 8;        // kstep 0 granule offset (u16 units)
  const int g1 = ((4 + hi) ^ sw) * 8;  // kstep 1
  const int awrow = wm * 128 + r15;
  const int bwrow = wn * 64 + r15;
  const u16* sA0 = &sA[0][0]; const u16* sA1 = &sA[1][0];
  const u16* sB0 = &sB[0][0]; const u16* sB1 = &sB[1][0];

  f32x4 acc[8][4] = {};
  bf16x8 aE[8], aO[8], b[8];

  // ---- prologue: T0 -> buf0 (8 chunks), T1 -> buf1 (6 of 8 chunks) ----
  STG_A(0, 0, 0); STG_A(0, 64, 0); STG_A(0, 128, 0); STG_A(0, 192, 0);
  STG_B(0, 0, 0); STG_B(0, 64, 0); STG_B(0, 128, 0); STG_B(0, 192, 0);
  STG_A(1, 0, 1); STG_A(1, 128, 1);
  STG_B(1, 0, 1); STG_B(1, 64, 1); STG_B(1, 128, 1); STG_B(1, 192, 1);
  asm volatile("s_waitcnt vmcnt(6)" ::: "memory");
  __builtin_amdgcn_sched_barrier(0);
  __builtin_amdgcn_s_barrier();
  // pre-read T0.A0 + T0.B01 (drained at P1's lgkmcnt(0))
  RD_A(sA0, 0, aE); RD_BH(sB0, 0);

  int kb = 0;
  auto iter = [&](auto lastc) {
    constexpr bool L = decltype(lastc)::value;
    const int kO = kb + 1, k2 = kb + 2, k3 = kb + 3;
    // P1: MM(0,0)=aE*b01; window: T0.B23; stage T1.A64/A192 (always)
    PH_BEGIN();
    RD_BH(sB0, 1);
    MMQ(0, 0, aE);
    PH_END();
    STG_A(1, 64, kO); STG_A(1, 192, kO);
    // P2: MM(0,1)=aE*b23; window: T0.A1 -> aO; stage T2.A0/A128
    PH_BEGIN();
    RD_A(sA0, 1, aO);
    MMQ(0, 1, aE);
    PH_END();
    if constexpr (!L) { STG_A(0, 0, k2); STG_A(0, 128, k2); }
    // P3: MM(1,0)=aO*b01; no window reads; stage T2.B0/B64; GATE buf1
    PH_BEGIN();
    MMQ(1, 0, aO);
    PH_END();
    if constexpr (!L) { STG_B(0, 0, k2); STG_B(0, 64, k2); GATE4(); }
    else              { GATE0(); }
    // P4: MM(1,1)=aO*b23; window: T1.A0 -> aE, T1.B01; stage T2.B128/B192
    PH_BEGIN();
    RD_A(sA1, 0, aE); RD_BH(sB1, 0);
    MMQ(1, 1, aO);
    PH_END();
    if constexpr (!L) { STG_B(0, 128, k2); STG_B(0, 192, k2); }
    // P5: MM(0,0)=aE*b01 (T1); window: T1.B23; stage T2.A64/A192
    PH_BEGIN();
    RD_BH(sB1, 1);
    MMQ(0, 0, aE);
    PH_END();
    if constexpr (!L) { STG_A(0, 64, k2); STG_A(0, 192, k2); }
    // P6: MM(0,1); window: T1.A1 -> aO; stage T3.A0/A128
    PH_BEGIN();
    RD_A(sA1, 1, aO);
    MMQ(0, 1, aE);
    PH_END();
    if constexpr (!L) { STG_A(1, 0, k3); STG_A(1, 128, k3); }
    // P7: MM(1,0); no window reads; stage T3.B0/B64; GATE buf0
    PH_BEGIN();
    MMQ(1, 0, aO);
    PH_END();
    if constexpr (!L) { STG_B(1, 0, k3); STG_B(1, 64, k3); GATE4(); }
    else              { GATE0(); }
    // P8: MM(1,1); window: T2.A0 -> aE, T2.B01; stage T3.B128/B192
    PH_BEGIN();
    if constexpr (!L) { RD_A(sA0, 0, aE); RD_BH(sB0, 0); }
    MMQ(1, 1, aO);
    PH_END();
    if constexpr (!L) { STG_B(1, 128, k3); STG_B(1, 192, k3); }
    kb += 2;
  };
  for (int i = 0; i < NITER - 1; ++i) iter(FalseT{});
  iter(TrueT{});

  // ---- epilogue ----
  if constexpr (WRITEV) {
    if (n0 >= 2 * kDM) {  // V third: write transposed+permuted into Vt
      const int hswap = ((hi & 1) << 1) | (hi >> 1);  // bits2<->3 of (s&15), /4
#pragma unroll
      for (int im = 0; im < 8; ++im) {
        const int m_base = m0 + wm * 128 + im * 16;   // 16-aligned
        const int bq = m_base >> 11;                  // batch
        const int sp = (m_base & (kS - 1)) + hswap * 4;
#pragma unroll
        for (int in = 0; in < 4; ++in) {
          const int c = n0 - 2 * kDM + wn * 64 + in * 16 + r15;
          const int hh = c >> 7, dd = c & 127;
          u16* dst = Vt + ((size_t)((bq * kH + hh) * kDK + dd)) * kS + sp;
          ushort4 pk;
          pk.x = f2bf(acc[im][in][0]); pk.y = f2bf(acc[im][in][1]);
          pk.z = f2bf(acc[im][in][2]); pk.w = f2bf(acc[im][in][3]);
          *reinterpret_cast<ushort4*>(dst) = pk;      // one 8B store
        }
      }
      return;
    }
  }
  const size_t crow0 = (size_t)(m0 + wm * 128 + hi * 4);
  const int col0 = n0 + wn * 64 + r15;
#pragma unroll
  for (int im = 0; im < 8; ++im)
#pragma unroll
    for (int in = 0; in < 4; ++in)
#pragma unroll
      for (int r = 0; r < 4; ++r)
        cstore(&C[(crow0 + im * 16 + r) * ldc + col0 + in * 16], acc[im][in][r]);
}

// ------- flash attention: 4 waves x QBLK=64 (256 q/block), KVBLK=64, swapped-QK ----
// Two q-halves per wave processed SEQUENTIALLY per tile (softmax transients
// reused -> fits the 256-VGPR cap at __launch_bounds__(256,2)). K/V LDS
// double-buffer identical to R6; Q direct global->registers. Grid 8x16x4 =
// 512 blocks = exactly 2/CU, one co-resident round; K/V HBM traffic halved.
__global__ __launch_bounds__(256, 2) void attn_kernel(const u16* __restrict__ qkv,
    const u16* __restrict__ vt, u16* __restrict__ attn_out) {
  __shared__ __align__(16) u16 lds[2][16384];
  const int tid = threadIdx.x;
  const int lane = tid & 63, wid = tid >> 6;
  const int l31 = lane & 31, hi5 = lane >> 5;
  const int q0 = blockIdx.x * 256, h = blockIdx.y, b = blockIdx.z;
  const int bh = b * kH + h;

  const int krow = tid >> 4, kg = tid & 15;
  const u16* kp = qkv + (size_t)(b * kS + krow) * kNQKV + kDM + h * kDK
                  + (size_t)((kg ^ (krow & 7)) * 8);
  const int vrow = tid >> 3, vg = tid & 7;
  const u16* vp = vt + (size_t)(bh * kDK + vrow) * kS + (size_t)((vg ^ (vrow & 7)) * 8);

  auto stage_kv = [&](u16* dst) {
#pragma unroll
    for (int i = 0; i < 4; ++i)
      GLOAD16(kp + (size_t)i * 16 * kNQKV, dst + (tid + 256 * i) * 8);
#pragma unroll
    for (int i = 0; i < 4; ++i)
      GLOAD16(vp + (size_t)i * 32 * kS, dst + 8192 + (tid + 256 * i) * 8);
    kp += (size_t)64 * kNQKV;
    vp += 64;
  };

  // Q fragments straight from global for both halves
  bf16x8 qfA[8], qfB[8];
  {
    const u16* qa = qkv + (size_t)(b * kS + q0 + wid * 64 + l31) * kNQKV
                    + h * kDK + hi5 * 8;
    const u16* qb = qa + (size_t)32 * kNQKV;
#pragma unroll
    for (int ds = 0; ds < 8; ++ds) {
      qfA[ds] = *reinterpret_cast<const bf16x8*>(qa + ds * 16);
      qfB[ds] = *reinterpret_cast<const bf16x8*>(qb + ds * 16);
    }
  }
  stage_kv(lds[0]);
  __syncthreads();

  f32x16 oA[4] = {}, oB[4] = {};
  float miA = -1e30f, liA = 0.f, miB = -1e30f, liB = 0.f;
  int cur = 0;

  // process one q-half against the tile in lds buffers Kb/Vb
  auto process = [&](const u16* Kb, const u16* Vb, bf16x8* qf, f32x16* o,
                     float& mi, float& li) {
    f32x16 s0 = {}, s1 = {};
    const int kr = l31;
#pragma unroll
    for (int ds = 0; ds < 8; ++ds) {
      int slot = ((ds * 2 + hi5) ^ (kr & 7)) * 8;
      bf16x8 k0 = lds_frag(&Kb[kr * 128 + slot]);
      bf16x8 k1 = lds_frag(&Kb[(32 + kr) * 128 + slot]);
      s0 = __builtin_amdgcn_mfma_f32_32x32x16_bf16(k0, qf[ds], s0, 0, 0, 0);
      s1 = __builtin_amdgcn_mfma_f32_32x32x16_bf16(k1, qf[ds], s1, 0, 0, 0);
    }

    float mx = s0[0];
#pragma unroll
    for (int r = 1; r < 16; ++r) mx = fmaxf(mx, s0[r]);
#pragma unroll
    for (int r = 0; r < 16; ++r) mx = fmaxf(mx, s1[r]);
    mx = fmaxf(mx, __shfl_xor(mx, 32));
    float mc = mx * kE2;
    if (__any(mc > mi + 8.0f)) {
      float mn = fmaxf(mi, mc);
      float corr = exp2_fast(mi - mn);
      mi = mn;
      li *= corr;
#pragma unroll
      for (int r = 0; r < 16; ++r) {
        float c = __shfl(corr, (r & 3) + 8 * (r >> 2) + 4 * hi5);
        o[0][r] *= c; o[1][r] *= c; o[2][r] *= c; o[3][r] *= c;
      }
    }
    float p0[16], p1[16];
    float rs = 0.f;
#pragma unroll
    for (int r = 0; r < 16; ++r) { p0[r] = exp2_fast(s0[r] * kE2 - mi); rs += p0[r]; }
#pragma unroll
    for (int r = 0; r < 16; ++r) { p1[r] = exp2_fast(s1[r] * kE2 - mi); rs += p1[r]; }
    rs += __shfl_xor(rs, 32);
    li += rs;

    u16x8 pw0, pw1, pw2, pw3;
#pragma unroll
    for (int r = 0; r < 8; ++r) {
      pw0[r] = f2bf(p0[r]);
      pw1[r] = f2bf(p0[r + 8]);
      pw2[r] = f2bf(p1[r]);
      pw3[r] = f2bf(p1[r + 8]);
    }
    bf16x8 pa[4] = {__builtin_bit_cast(bf16x8, pw0), __builtin_bit_cast(bf16x8, pw1),
                    __builtin_bit_cast(bf16x8, pw2), __builtin_bit_cast(bf16x8, pw3)};

#pragma unroll
    for (int dt = 0; dt < 4; ++dt) {
      const int row = dt * 32 + l31;
      const int rs8 = row & 7;
#pragma unroll
      for (int ks = 0; ks < 4; ++ks) {
        bf16x8 bv = lds_frag(&Vb[row * 64 + ((ks * 2 + hi5) ^ rs8) * 8]);
        o[dt] = __builtin_amdgcn_mfma_f32_32x32x16_bf16(pa[ks], bv, o[dt], 0, 0, 0);
      }
    }
  };

  for (int t = 0; t < kS / 64; ++t) {
    if (t < kS / 64 - 1) stage_kv(lds[cur ^ 1]);

    const u16* Kb = (const u16*)lds[cur];
    const u16* Vb = Kb + 8192;
    process(Kb, Vb, qfA, oA, miA, liA);
    process(Kb, Vb, qfB, oB, miB, liB);

    __syncthreads();
    cur ^= 1;
  }

  // ---- epilogue: normalize, store bf16 [row q][col h*128+d] ----
  const size_t obase = (size_t)(b * kS + q0 + wid * 64) * kDM + h * kDK + l31;
  float rliA = 1.0f / liA, rliB = 1.0f / liB;
#pragma unroll
  for (int r = 0; r < 16; ++r) {
    int ql = (r & 3) + 8 * (r >> 2) + 4 * hi5;
    float wA = __shfl(rliA, ql);
    float wB = __shfl(rliB, ql);
#pragma unroll
    for (int dt = 0; dt < 4; ++dt) {
      attn_out[obase + (size_t)ql * kDM + dt * 32] = f2bf(oA[dt][r] * wA);
      attn_out[obase + (size_t)(32 + ql) * kDM + dt * 32] = f2bf(oB[dt][r] * wB);
    }
  }
}

// ---------------------------------------------------------------------------
extern "C" void kernel_launch(void* const* d_in, const int* in_sizes, int n_in,
                              void* d_out, int out_size, void* d_ws, size_t ws_size,
                              hipStream_t stream) {
  (void)in_sizes; (void)n_in; (void)out_size; (void)ws_size;
  const float* x  = (const float*)d_in[0];
  const float* wq = (const float*)d_in[1];
  const float* wk = (const float*)d_in[2];
  const float* wv = (const float*)d_in[3];
  const float* wo = (const float*)d_in[4];

  char* p = (char*)d_ws;
  u16* xb   = (u16*)p; p += (size_t)kM * kDM * 2;
  u16* wtc  = (u16*)p; p += (size_t)kNQKV * kDM * 2;
  u16* wot  = (u16*)p; p += (size_t)kDM * kDM * 2;
  u16* qkvb = (u16*)p; p += (size_t)kM * kNQKV * 2;
  u16* vtb  = (u16*)p; p += (size_t)kB * kH * kDK * kS * 2;
  u16* aob  = xb;  // reuse: x_bf16 dead after QKV gemm

  int n4 = kM * kDM / 4;
  cast_x_kernel<<<(n4 + 255) / 256, 256, 0, stream>>>(x, xb, n4);
  transpose_w_kernel<<<dim3(kDM / 32, kDM / 32, 4), dim3(32, 8), 0, stream>>>(
      wq, wk, wv, wo, wtc, wot);
  gemm256_kernel<u16, true><<<dim3(kNQKV / 256, kM / 256), 512, 0, stream>>>(
      xb, wtc, qkvb, vtb, kDM, kDM, kDM, kNQKV);
  attn_kernel<<<dim3(kS / 256, kH, kB), 256, 0, stream>>>(qkvb, vtb, aob);
  gemm256_kernel<float, false><<<dim3(kDM / 256, kM / 256), 512, 0, stream>>>(
      aob, wot, (float*)d_out, nullptr, kDM, kDM, kDM, kDM);
}

// Round 11
// 580.305 us; speedup vs baseline: 1.4174x; 1.4174x over previous
//
#include <hip/hip_runtime.h>
#include <hip/hip_bf16.h>

typedef __attribute__((ext_vector_type(8))) __bf16 bf16x8;
typedef __attribute__((ext_vector_type(4))) float f32x4;
typedef __attribute__((ext_vector_type(16))) float f32x16;
typedef __attribute__((ext_vector_type(8))) unsigned short u16x8;
typedef unsigned short u16;

#define DEVINL static __device__ __forceinline__

namespace {
constexpr int kB = 4;
constexpr int kS = 2048;
constexpr int kDM = 2048;
constexpr int kH = 16;
constexpr int kDK = 128;
constexpr int kM = kB * kS;        // 8192
constexpr int kNQKV = 3 * kDM;     // 6144
constexpr float kE2 = 0.08838834764831845f * 1.44269504088896f; // scale*log2(e)
}

DEVINL u16 f2bf(float f) {
  __hip_bfloat16 h = __float2bfloat16(f);
  return __builtin_bit_cast(u16, h);
}

#if __has_builtin(__builtin_amdgcn_exp2f)
DEVINL float exp2_fast(float x) { return __builtin_amdgcn_exp2f(x); }
#else
DEVINL float exp2_fast(float x) { return exp2f(x); }
#endif

#define GLOAD16(gp, lp) \
  __builtin_amdgcn_global_load_lds((const __attribute__((address_space(1))) void*)(gp), \
                                   (__attribute__((address_space(3))) void*)(lp), 16, 0, 0)

DEVINL bf16x8 lds_frag(const u16* p) { return *reinterpret_cast<const bf16x8*>(p); }

DEVINL f32x4 MFMA16x16(bf16x8 a, bf16x8 b, f32x4 c) {
  return __builtin_amdgcn_mfma_f32_16x16x32_bf16(a, b, c, 0, 0, 0);
}

struct TrueT { static constexpr bool value = true; };
struct FalseT { static constexpr bool value = false; };

// ---------------- cast x: fp32 -> bf16, x4 vectorized ----------------
__global__ __launch_bounds__(256) void cast_x_kernel(const float* __restrict__ x,
                                                     u16* __restrict__ o, int n4) {
  int i = blockIdx.x * 256 + threadIdx.x;
  if (i >= n4) return;
  float4 v = reinterpret_cast<const float4*>(x)[i];
  ushort4 r;
  r.x = f2bf(v.x); r.y = f2bf(v.y); r.z = f2bf(v.z); r.w = f2bf(v.w);
  reinterpret_cast<ushort4*>(o)[i] = r;
}

// ------------- transpose + cast weights: w[k][n] fp32 -> wt[n][k] bf16 -------------
__global__ __launch_bounds__(256) void transpose_w_kernel(const float* __restrict__ w0,
    const float* __restrict__ w1, const float* __restrict__ w2, const float* __restrict__ w3,
    u16* __restrict__ wtcat, u16* __restrict__ wot) {
  const float* src = (blockIdx.z == 0) ? w0 : (blockIdx.z == 1) ? w1
                    : (blockIdx.z == 2) ? w2 : w3;
  u16* dst = (blockIdx.z < 3) ? (wtcat + (size_t)blockIdx.z * kDM * kDM) : wot;
  __shared__ float tile[32][33];
  int n0 = blockIdx.x * 32, k0 = blockIdx.y * 32;
  int tx = threadIdx.x, ty = threadIdx.y;
#pragma unroll
  for (int i = 0; i < 4; ++i)
    tile[ty + i * 8][tx] = src[(size_t)(k0 + ty + i * 8) * kDM + n0 + tx];
  __syncthreads();
#pragma unroll
  for (int i = 0; i < 4; ++i)
    dst[(size_t)(n0 + ty + i * 8) * kDM + k0 + tx] = f2bf(tile[tx][ty + i * 8]);
}

// ===================== 256x256 8-phase GEMM (Bt layout), 16x16x32 MFMA ======
// Single barrier per phase (R9). Stage slotting R5; gates vmcnt(4) at P3/P7.
DEVINL void cstore(float* p, float v) { *p = v; }
DEVINL void cstore(u16* p, float v) { *p = f2bf(v); }

#define PH_BEGIN()                                     \
  __builtin_amdgcn_sched_barrier(0);                   \
  __builtin_amdgcn_s_barrier();                        \
  asm volatile("s_waitcnt lgkmcnt(0)" ::: "memory");   \
  __builtin_amdgcn_sched_barrier(0);                   \
  __builtin_amdgcn_s_setprio(1)

#define PH_END()                                       \
  __builtin_amdgcn_s_setprio(0);                       \
  __builtin_amdgcn_sched_barrier(0)

#define GATE4() \
  asm volatile("s_waitcnt vmcnt(4)" ::: "memory");     \
  __builtin_amdgcn_sched_barrier(0)

#define GATE0() \
  asm volatile("s_waitcnt vmcnt(0)" ::: "memory");     \
  __builtin_amdgcn_sched_barrier(0)

// read A-half MQ of tile buffer SB into DST[0..7]
#define RD_A(SB, MQ, DST)                                             \
  do {                                                                \
    _Pragma("unroll") for (int mf = 0; mf < 4; ++mf) {                \
      const u16* p_ = (SB) + (awrow + (MQ) * 64 + mf * 16) * 64;      \
      DST[mf * 2 + 0] = lds_frag(p_ + g0);                            \
      DST[mf * 2 + 1] = lds_frag(p_ + g1);                            \
    }                                                                 \
  } while (0)

// read B-half NH of tile buffer SB into b[NH*4 .. NH*4+3]
#define RD_BH(SB, NH)                                                 \
  do {                                                                \
    _Pragma("unroll") for (int nf = 0; nf < 2; ++nf) {                \
      const u16* p_ = (SB) + (bwrow + (NH) * 32 + nf * 16) * 64;      \
      b[(NH) * 4 + nf * 2 + 0] = lds_frag(p_ + g0);                   \
      b[(NH) * 4 + nf * 2 + 1] = lds_frag(p_ + g1);                   \
    }                                                                 \
  } while (0)

#define MMQ(MQ, NH, AF)                                               \
  do {                                                                \
    _Pragma("unroll") for (int mf = 0; mf < 4; ++mf)                  \
      _Pragma("unroll") for (int nf = 0; nf < 2; ++nf) {              \
        f32x4 t_ = acc[(MQ) * 4 + mf][(NH) * 2 + nf];                 \
        t_ = MFMA16x16(AF[mf * 2 + 0], b[(NH) * 4 + nf * 2 + 0], t_); \
        t_ = MFMA16x16(AF[mf * 2 + 1], b[(NH) * 4 + nf * 2 + 1], t_); \
        acc[(MQ) * 4 + mf][(NH) * 2 + nf] = t_;                       \
      }                                                               \
  } while (0)

#define STG_A(buf, R0, kt) \
  GLOAD16(baseA + (size_t)(R0) * lda + (size_t)(kt) * 64, ldsA + (buf) * 16384 + (R0) * 64)
#define STG_B(buf, R0, kt) \
  GLOAD16(baseB + (size_t)(R0) * ldb + (size_t)(kt) * 64, ldsB + (buf) * 16384 + (R0) * 64)

template <typename CT, bool WRITEV>
__global__ __launch_bounds__(512, 2) void gemm256_kernel(const u16* __restrict__ A,
    const u16* __restrict__ Bt, CT* __restrict__ C, u16* __restrict__ Vt,
    int K, int lda, int ldb, int ldc) {
  __shared__ __align__(16) u16 sA[2][16384];
  __shared__ __align__(16) u16 sB[2][16384];
  const int tid = threadIdx.x;
  const int lane = tid & 63, wid = tid >> 6;
  const int r15 = lane & 15, hi = lane >> 4;
  const int wm = wid >> 2, wn = wid & 3;

  // XCD-aware bijective swizzle (nwg % 8 == 0 for both launches)
  const int gx = gridDim.x, nwg = gx * gridDim.y;
  const int orig = blockIdx.y * gx + blockIdx.x;
  const int wg = (orig & 7) * (nwg >> 3) + (orig >> 3);
  const int n0 = (wg % gx) * 256;
  const int m0 = (wg / gx) * 256;

  const int NT = K >> 6;       // 64-wide k tiles (even)
  const int NITER = NT >> 1;

  // staging: thread stages 1 granule (16B) per 64-row chunk
  const int rc = tid >> 3;                         // row within chunk
  const int cg = (tid & 7) ^ (rc & 7);             // logical source granule
  const u16* baseA = A + (size_t)(m0 + rc) * lda + cg * 8;
  const u16* baseB = Bt + (size_t)(n0 + rc) * ldb + cg * 8;
  u16* ldsA = &sA[0][0] + rc * 64 + (tid & 7) * 8; // linear physical dest
  u16* ldsB = &sB[0][0] + rc * 64 + (tid & 7) * 8;

  // per-thread-constant read swizzle: row&7 == r15&7 for all fragment rows
  const int sw = r15 & 7;
  const int g0 = (hi ^ sw) * 8;        // kstep 0 granule offset (u16 units)
  const int g1 = ((4 + hi) ^ sw) * 8;  // kstep 1
  const int awrow = wm * 128 + r15;
  const int bwrow = wn * 64 + r15;
  const u16* sA0 = &sA[0][0]; const u16* sA1 = &sA[1][0];
  const u16* sB0 = &sB[0][0]; const u16* sB1 = &sB[1][0];

  f32x4 acc[8][4] = {};
  bf16x8 aE[8], aO[8], b[8];

  // ---- prologue: T0 -> buf0 (8 chunks), T1 -> buf1 (6 of 8 chunks) ----
  STG_A(0, 0, 0); STG_A(0, 64, 0); STG_A(0, 128, 0); STG_A(0, 192, 0);
  STG_B(0, 0, 0); STG_B(0, 64, 0); STG_B(0, 128, 0); STG_B(0, 192, 0);
  STG_A(1, 0, 1); STG_A(1, 128, 1);
  STG_B(1, 0, 1); STG_B(1, 64, 1); STG_B(1, 128, 1); STG_B(1, 192, 1);
  asm volatile("s_waitcnt vmcnt(6)" ::: "memory");
  __builtin_amdgcn_sched_barrier(0);
  __builtin_amdgcn_s_barrier();
  // pre-read T0.A0 + T0.B01 (drained at P1's lgkmcnt(0))
  RD_A(sA0, 0, aE); RD_BH(sB0, 0);

  int kb = 0;
  auto iter = [&](auto lastc) {
    constexpr bool L = decltype(lastc)::value;
    const int kO = kb + 1, k2 = kb + 2, k3 = kb + 3;
    // P1: MM(0,0)=aE*b01; window: T0.B23; stage T1.A64/A192 (always)
    PH_BEGIN();
    RD_BH(sB0, 1);
    MMQ(0, 0, aE);
    PH_END();
    STG_A(1, 64, kO); STG_A(1, 192, kO);
    // P2: MM(0,1)=aE*b23; window: T0.A1 -> aO; stage T2.A0/A128
    PH_BEGIN();
    RD_A(sA0, 1, aO);
    MMQ(0, 1, aE);
    PH_END();
    if constexpr (!L) { STG_A(0, 0, k2); STG_A(0, 128, k2); }
    // P3: MM(1,0)=aO*b01; no window reads; stage T2.B0/B64; GATE buf1
    PH_BEGIN();
    MMQ(1, 0, aO);
    PH_END();
    if constexpr (!L) { STG_B(0, 0, k2); STG_B(0, 64, k2); GATE4(); }
    else              { GATE0(); }
    // P4: MM(1,1)=aO*b23; window: T1.A0 -> aE, T1.B01; stage T2.B128/B192
    PH_BEGIN();
    RD_A(sA1, 0, aE); RD_BH(sB1, 0);
    MMQ(1, 1, aO);
    PH_END();
    if constexpr (!L) { STG_B(0, 128, k2); STG_B(0, 192, k2); }
    // P5: MM(0,0)=aE*b01 (T1); window: T1.B23; stage T2.A64/A192
    PH_BEGIN();
    RD_BH(sB1, 1);
    MMQ(0, 0, aE);
    PH_END();
    if constexpr (!L) { STG_A(0, 64, k2); STG_A(0, 192, k2); }
    // P6: MM(0,1); window: T1.A1 -> aO; stage T3.A0/A128
    PH_BEGIN();
    RD_A(sA1, 1, aO);
    MMQ(0, 1, aE);
    PH_END();
    if constexpr (!L) { STG_A(1, 0, k3); STG_A(1, 128, k3); }
    // P7: MM(1,0); no window reads; stage T3.B0/B64; GATE buf0
    PH_BEGIN();
    MMQ(1, 0, aO);
    PH_END();
    if constexpr (!L) { STG_B(1, 0, k3); STG_B(1, 64, k3); GATE4(); }
    else              { GATE0(); }
    // P8: MM(1,1); window: T2.A0 -> aE, T2.B01; stage T3.B128/B192
    PH_BEGIN();
    if constexpr (!L) { RD_A(sA0, 0, aE); RD_BH(sB0, 0); }
    MMQ(1, 1, aO);
    PH_END();
    if constexpr (!L) { STG_B(1, 128, k3); STG_B(1, 192, k3); }
    kb += 2;
  };
  for (int i = 0; i < NITER - 1; ++i) iter(FalseT{});
  iter(TrueT{});

  // ---- epilogue ----
  if constexpr (WRITEV) {
    if (n0 >= 2 * kDM) {  // V third: write transposed+permuted into Vt
      const int hswap = ((hi & 1) << 1) | (hi >> 1);  // bits2<->3 of (s&15), /4
#pragma unroll
      for (int im = 0; im < 8; ++im) {
        const int m_base = m0 + wm * 128 + im * 16;   // 16-aligned
        const int bq = m_base >> 11;                  // batch
        const int sp = (m_base & (kS - 1)) + hswap * 4;
#pragma unroll
        for (int in = 0; in < 4; ++in) {
          const int c = n0 - 2 * kDM + wn * 64 + in * 16 + r15;
          const int hh = c >> 7, dd = c & 127;
          u16* dst = Vt + ((size_t)((bq * kH + hh) * kDK + dd)) * kS + sp;
          ushort4 pk;
          pk.x = f2bf(acc[im][in][0]); pk.y = f2bf(acc[im][in][1]);
          pk.z = f2bf(acc[im][in][2]); pk.w = f2bf(acc[im][in][3]);
          *reinterpret_cast<ushort4*>(dst) = pk;      // one 8B store
        }
      }
      return;
    }
  }
  const size_t crow0 = (size_t)(m0 + wm * 128 + hi * 4);
  const int col0 = n0 + wn * 64 + r15;
#pragma unroll
  for (int im = 0; im < 8; ++im)
#pragma unroll
    for (int in = 0; in < 4; ++in)
#pragma unroll
      for (int r = 0; r < 4; ++r)
        cstore(&C[(crow0 + im * 16 + r) * ldc + col0 + in * 16], acc[im][in][r]);
}

// ------- flash attention: 4 waves x QBLK=64 (256 q/block), swapped-QK 32x32 ----
// Two q-halves per wave, MACRO-expanded (no lambdas/pointer params: R10's
// pointer-passed arrays defeated SROA -> scratch). Halves run sequentially
// through QK+softmax (transients reused); PV is a single shared loop where
// each V ds_read feeds BOTH halves' MFMA. Grid 8x16x4 = 512 blocks = 2/CU,
// one co-resident round. K/V HBM fetch per head halved vs QBLK=32.
#define QKSM(QF, O, MI, LI, PA)                                            \
  do {                                                                     \
    f32x16 s0_ = {}, s1_ = {};                                             \
    _Pragma("unroll")                                                      \
    for (int ds = 0; ds < 8; ++ds) {                                       \
      int slot_ = ((ds * 2 + hi5) ^ (l31 & 7)) * 8;                        \
      bf16x8 k0_ = lds_frag(&Kb[l31 * 128 + slot_]);                       \
      bf16x8 k1_ = lds_frag(&Kb[(32 + l31) * 128 + slot_]);                \
      s0_ = __builtin_amdgcn_mfma_f32_32x32x16_bf16(k0_, QF[ds], s0_, 0, 0, 0); \
      s1_ = __builtin_amdgcn_mfma_f32_32x32x16_bf16(k1_, QF[ds], s1_, 0, 0, 0); \
    }                                                                      \
    float mx_ = s0_[0];                                                    \
    _Pragma("unroll") for (int r = 1; r < 16; ++r) mx_ = fmaxf(mx_, s0_[r]); \
    _Pragma("unroll") for (int r = 0; r < 16; ++r) mx_ = fmaxf(mx_, s1_[r]); \
    mx_ = fmaxf(mx_, __shfl_xor(mx_, 32));                                 \
    float mc_ = mx_ * kE2;                                                 \
    if (__any(mc_ > MI + 8.0f)) {                                          \
      float mn_ = fmaxf(MI, mc_);                                          \
      float corr_ = exp2_fast(MI - mn_);                                   \
      MI = mn_; LI *= corr_;                                               \
      _Pragma("unroll") for (int r = 0; r < 16; ++r) {                     \
        float c_ = __shfl(corr_, (r & 3) + 8 * (r >> 2) + 4 * hi5);        \
        O[0][r] *= c_; O[1][r] *= c_; O[2][r] *= c_; O[3][r] *= c_;        \
      }                                                                    \
    }                                                                      \
    float rs_ = 0.f;                                                       \
    u16x8 pw0_, pw1_, pw2_, pw3_;                                          \
    _Pragma("unroll") for (int r = 0; r < 8; ++r) {                        \
      float pa_ = exp2_fast(s0_[r] * kE2 - MI);                            \
      float pb_ = exp2_fast(s0_[r + 8] * kE2 - MI);                        \
      float pc_ = exp2_fast(s1_[r] * kE2 - MI);                            \
      float pd_ = exp2_fast(s1_[r + 8] * kE2 - MI);                        \
      rs_ += pa_ + pb_ + pc_ + pd_;                                        \
      pw0_[r] = f2bf(pa_); pw1_[r] = f2bf(pb_);                            \
      pw2_[r] = f2bf(pc_); pw3_[r] = f2bf(pd_);                            \
    }                                                                      \
    rs_ += __shfl_xor(rs_, 32);                                            \
    LI += rs_;                                                             \
    PA[0] = __builtin_bit_cast(bf16x8, pw0_);                              \
    PA[1] = __builtin_bit_cast(bf16x8, pw1_);                              \
    PA[2] = __builtin_bit_cast(bf16x8, pw2_);                              \
    PA[3] = __builtin_bit_cast(bf16x8, pw3_);                              \
  } while (0)

__global__ __launch_bounds__(256, 2) void attn_kernel(const u16* __restrict__ qkv,
    const u16* __restrict__ vt, u16* __restrict__ attn_out) {
  __shared__ __align__(16) u16 lds[2][16384];
  const int tid = threadIdx.x;
  const int lane = tid & 63, wid = tid >> 6;
  const int l31 = lane & 31, hi5 = lane >> 5;
  const int q0 = blockIdx.x * 256, h = blockIdx.y, b = blockIdx.z;
  const int bh = b * kH + h;

  const int krow = tid >> 4, kg = tid & 15;
  const u16* kp = qkv + (size_t)(b * kS + krow) * kNQKV + kDM + h * kDK
                  + (size_t)((kg ^ (krow & 7)) * 8);
  const int vrow = tid >> 3, vg = tid & 7;
  const u16* vp = vt + (size_t)(bh * kDK + vrow) * kS + (size_t)((vg ^ (vrow & 7)) * 8);

  auto stage_kv = [&](u16* dst) {
#pragma unroll
    for (int i = 0; i < 4; ++i)
      GLOAD16(kp + (size_t)i * 16 * kNQKV, dst + (tid + 256 * i) * 8);
#pragma unroll
    for (int i = 0; i < 4; ++i)
      GLOAD16(vp + (size_t)i * 32 * kS, dst + 8192 + (tid + 256 * i) * 8);
    kp += (size_t)64 * kNQKV;
    vp += 64;
  };

  // Q fragments straight from global for both halves (named arrays, const idx)
  bf16x8 qfA[8], qfB[8];
  {
    const u16* qa = qkv + (size_t)(b * kS + q0 + wid * 64 + l31) * kNQKV
                    + h * kDK + hi5 * 8;
    const u16* qb = qa + (size_t)32 * kNQKV;
#pragma unroll
    for (int ds = 0; ds < 8; ++ds) {
      qfA[ds] = *reinterpret_cast<const bf16x8*>(qa + ds * 16);
      qfB[ds] = *reinterpret_cast<const bf16x8*>(qb + ds * 16);
    }
  }
  stage_kv(lds[0]);
  __syncthreads();

  f32x16 oA[4] = {}, oB[4] = {};
  float miA = -1e30f, liA = 0.f, miB = -1e30f, liB = 0.f;
  int cur = 0;

  for (int t = 0; t < kS / 64; ++t) {
    if (t < kS / 64 - 1) stage_kv(lds[cur ^ 1]);

    const u16* Kb = (const u16*)lds[cur];
    const u16* Vb = Kb + 8192;

    bf16x8 paA[4], paB[4];
    QKSM(qfA, oA, miA, liA, paA);
    QKSM(qfB, oB, miB, liB, paB);

    // ---- shared PV: each V read feeds both halves ----
#pragma unroll
    for (int dt = 0; dt < 4; ++dt) {
      const int row = dt * 32 + l31;
      const int rs8 = row & 7;
#pragma unroll
      for (int ks = 0; ks < 4; ++ks) {
        bf16x8 bv = lds_frag(&Vb[row * 64 + ((ks * 2 + hi5) ^ rs8) * 8]);
        oA[dt] = __builtin_amdgcn_mfma_f32_32x32x16_bf16(paA[ks], bv, oA[dt], 0, 0, 0);
        oB[dt] = __builtin_amdgcn_mfma_f32_32x32x16_bf16(paB[ks], bv, oB[dt], 0, 0, 0);
      }
    }

    __syncthreads();
    cur ^= 1;
  }

  // ---- epilogue: normalize, store bf16 [row q][col h*128+d] ----
  const size_t obase = (size_t)(b * kS + q0 + wid * 64) * kDM + h * kDK + l31;
  float rliA = 1.0f / liA, rliB = 1.0f / liB;
#pragma unroll
  for (int r = 0; r < 16; ++r) {
    int ql = (r & 3) + 8 * (r >> 2) + 4 * hi5;
    float wA = __shfl(rliA, ql);
    float wB = __shfl(rliB, ql);
#pragma unroll
    for (int dt = 0; dt < 4; ++dt) {
      attn_out[obase + (size_t)ql * kDM + dt * 32] = f2bf(oA[dt][r] * wA);
      attn_out[obase + (size_t)(32 + ql) * kDM + dt * 32] = f2bf(oB[dt][r] * wB);
    }
  }
}

// ---------------------------------------------------------------------------
extern "C" void kernel_launch(void* const* d_in, const int* in_sizes, int n_in,
                              void* d_out, int out_size, void* d_ws, size_t ws_size,
                              hipStream_t stream) {
  (void)in_sizes; (void)n_in; (void)out_size; (void)ws_size;
  const float* x  = (const float*)d_in[0];
  const float* wq = (const float*)d_in[1];
  const float* wk = (const float*)d_in[2];
  const float* wv = (const float*)d_in[3];
  const float* wo = (const float*)d_in[4];

  char* p = (char*)d_ws;
  u16* xb   = (u16*)p; p += (size_t)kM * kDM * 2;
  u16* wtc  = (u16*)p; p += (size_t)kNQKV * kDM * 2;
  u16* wot  = (u16*)p; p += (size_t)kDM * kDM * 2;
  u16* qkvb = (u16*)p; p += (size_t)kM * kNQKV * 2;
  u16* vtb  = (u16*)p; p += (size_t)kB * kH * kDK * kS * 2;
  u16* aob  = xb;  // reuse: x_bf16 dead after QKV gemm

  int n4 = kM * kDM / 4;
  cast_x_kernel<<<(n4 + 255) / 256, 256, 0, stream>>>(x, xb, n4);
  transpose_w_kernel<<<dim3(kDM / 32, kDM / 32, 4), dim3(32, 8), 0, stream>>>(
      wq, wk, wv, wo, wtc, wot);
  gemm256_kernel<u16, true><<<dim3(kNQKV / 256, kM / 256), 512, 0, stream>>>(
      xb, wtc, qkvb, vtb, kDM, kDM, kDM, kNQKV);
  attn_kernel<<<dim3(kS / 256, kH, kB), 256, 0, stream>>>(qkvb, vtb, aob);
  gemm256_kernel<float, false><<<dim3(kDM / 256, kM / 256), 512, 0, stream>>>(
      aob, wot, (float*)d_out, nullptr, kDM, kDM, kDM, kDM);
}

// Round 12
// 479.485 us; speedup vs baseline: 1.7154x; 1.2103x over previous
//
#include <hip/hip_runtime.h>
#include <hip/hip_bf16.h>

typedef __attribute__((ext_vector_type(8))) __bf16 bf16x8;
typedef __attribute__((ext_vector_type(4))) float f32x4;
typedef __attribute__((ext_vector_type(16))) float f32x16;
typedef __attribute__((ext_vector_type(8))) unsigned short u16x8;
typedef unsigned short u16;

#define DEVINL static __device__ __forceinline__

namespace {
constexpr int kB = 4;
constexpr int kS = 2048;
constexpr int kDM = 2048;
constexpr int kH = 16;
constexpr int kDK = 128;
constexpr int kM = kB * kS;        // 8192
constexpr int kNQKV = 3 * kDM;     // 6144
constexpr float kE2 = 0.08838834764831845f * 1.44269504088896f; // scale*log2(e)
}

DEVINL u16 f2bf(float f) {
  __hip_bfloat16 h = __float2bfloat16(f);
  return __builtin_bit_cast(u16, h);
}

#if __has_builtin(__builtin_amdgcn_exp2f)
DEVINL float exp2_fast(float x) { return __builtin_amdgcn_exp2f(x); }
#else
DEVINL float exp2_fast(float x) { return exp2f(x); }
#endif

#define GLOAD16(gp, lp) \
  __builtin_amdgcn_global_load_lds((const __attribute__((address_space(1))) void*)(gp), \
                                   (__attribute__((address_space(3))) void*)(lp), 16, 0, 0)

DEVINL bf16x8 lds_frag(const u16* p) { return *reinterpret_cast<const bf16x8*>(p); }

DEVINL f32x4 MFMA16x16(bf16x8 a, bf16x8 b, f32x4 c) {
  return __builtin_amdgcn_mfma_f32_16x16x32_bf16(a, b, c, 0, 0, 0);
}

struct TrueT { static constexpr bool value = true; };
struct FalseT { static constexpr bool value = false; };

// ---------------- cast x: fp32 -> bf16, x4 vectorized ----------------
__global__ __launch_bounds__(256) void cast_x_kernel(const float* __restrict__ x,
                                                     u16* __restrict__ o, int n4) {
  int i = blockIdx.x * 256 + threadIdx.x;
  if (i >= n4) return;
  float4 v = reinterpret_cast<const float4*>(x)[i];
  ushort4 r;
  r.x = f2bf(v.x); r.y = f2bf(v.y); r.z = f2bf(v.z); r.w = f2bf(v.w);
  reinterpret_cast<ushort4*>(o)[i] = r;
}

// ------------- transpose + cast weights: w[k][n] fp32 -> wt[n][k] bf16 -------------
__global__ __launch_bounds__(256) void transpose_w_kernel(const float* __restrict__ w0,
    const float* __restrict__ w1, const float* __restrict__ w2, const float* __restrict__ w3,
    u16* __restrict__ wtcat, u16* __restrict__ wot) {
  const float* src = (blockIdx.z == 0) ? w0 : (blockIdx.z == 1) ? w1
                    : (blockIdx.z == 2) ? w2 : w3;
  u16* dst = (blockIdx.z < 3) ? (wtcat + (size_t)blockIdx.z * kDM * kDM) : wot;
  __shared__ float tile[32][33];
  int n0 = blockIdx.x * 32, k0 = blockIdx.y * 32;
  int tx = threadIdx.x, ty = threadIdx.y;
#pragma unroll
  for (int i = 0; i < 4; ++i)
    tile[ty + i * 8][tx] = src[(size_t)(k0 + ty + i * 8) * kDM + n0 + tx];
  __syncthreads();
#pragma unroll
  for (int i = 0; i < 4; ++i)
    dst[(size_t)(n0 + ty + i * 8) * kDM + k0 + tx] = f2bf(tile[tx][ty + i * 8]);
}

// ===================== 256x256 8-phase GEMM (Bt layout), 16x16x32 MFMA ======
// Single barrier per phase (R9). Stage slotting R5; gates vmcnt(4) at P3/P7.
DEVINL void cstore(float* p, float v) { *p = v; }
DEVINL void cstore(u16* p, float v) { *p = f2bf(v); }

#define PH_BEGIN()                                     \
  __builtin_amdgcn_sched_barrier(0);                   \
  __builtin_amdgcn_s_barrier();                        \
  asm volatile("s_waitcnt lgkmcnt(0)" ::: "memory");   \
  __builtin_amdgcn_sched_barrier(0);                   \
  __builtin_amdgcn_s_setprio(1)

#define PH_END()                                       \
  __builtin_amdgcn_s_setprio(0);                       \
  __builtin_amdgcn_sched_barrier(0)

#define GATE4() \
  asm volatile("s_waitcnt vmcnt(4)" ::: "memory");     \
  __builtin_amdgcn_sched_barrier(0)

#define GATE0() \
  asm volatile("s_waitcnt vmcnt(0)" ::: "memory");     \
  __builtin_amdgcn_sched_barrier(0)

// read A-half MQ of tile buffer SB into DST[0..7]
#define RD_A(SB, MQ, DST)                                             \
  do {                                                                \
    _Pragma("unroll") for (int mf = 0; mf < 4; ++mf) {                \
      const u16* p_ = (SB) + (awrow + (MQ) * 64 + mf * 16) * 64;      \
      DST[mf * 2 + 0] = lds_frag(p_ + g0);                            \
      DST[mf * 2 + 1] = lds_frag(p_ + g1);                            \
    }                                                                 \
  } while (0)

// read B-half NH of tile buffer SB into b[NH*4 .. NH*4+3]
#define RD_BH(SB, NH)                                                 \
  do {                                                                \
    _Pragma("unroll") for (int nf = 0; nf < 2; ++nf) {                \
      const u16* p_ = (SB) + (bwrow + (NH) * 32 + nf * 16) * 64;      \
      b[(NH) * 4 + nf * 2 + 0] = lds_frag(p_ + g0);                   \
      b[(NH) * 4 + nf * 2 + 1] = lds_frag(p_ + g1);                   \
    }                                                                 \
  } while (0)

#define MMQ(MQ, NH, AF)                                               \
  do {                                                                \
    _Pragma("unroll") for (int mf = 0; mf < 4; ++mf)                  \
      _Pragma("unroll") for (int nf = 0; nf < 2; ++nf) {              \
        f32x4 t_ = acc[(MQ) * 4 + mf][(NH) * 2 + nf];                 \
        t_ = MFMA16x16(AF[mf * 2 + 0], b[(NH) * 4 + nf * 2 + 0], t_); \
        t_ = MFMA16x16(AF[mf * 2 + 1], b[(NH) * 4 + nf * 2 + 1], t_); \
        acc[(MQ) * 4 + mf][(NH) * 2 + nf] = t_;                       \
      }                                                               \
  } while (0)

#define STG_A(buf, R0, kt) \
  GLOAD16(baseA + (size_t)(R0) * lda + (size_t)(kt) * 64, ldsA + (buf) * 16384 + (R0) * 64)
#define STG_B(buf, R0, kt) \
  GLOAD16(baseB + (size_t)(R0) * ldb + (size_t)(kt) * 64, ldsB + (buf) * 16384 + (R0) * 64)

template <typename CT, bool WRITEV>
__global__ __launch_bounds__(512, 2) void gemm256_kernel(const u16* __restrict__ A,
    const u16* __restrict__ Bt, CT* __restrict__ C, u16* __restrict__ Vt,
    int K, int lda, int ldb, int ldc) {
  __shared__ __align__(16) u16 sA[2][16384];
  __shared__ __align__(16) u16 sB[2][16384];
  const int tid = threadIdx.x;
  const int lane = tid & 63, wid = tid >> 6;
  const int r15 = lane & 15, hi = lane >> 4;
  const int wm = wid >> 2, wn = wid & 3;

  // XCD-aware bijective swizzle (nwg % 8 == 0 for both launches)
  const int gx = gridDim.x, nwg = gx * gridDim.y;
  const int orig = blockIdx.y * gx + blockIdx.x;
  const int wg = (orig & 7) * (nwg >> 3) + (orig >> 3);
  const int n0 = (wg % gx) * 256;
  const int m0 = (wg / gx) * 256;

  const int NT = K >> 6;       // 64-wide k tiles (even)
  const int NITER = NT >> 1;

  // staging: thread stages 1 granule (16B) per 64-row chunk
  const int rc = tid >> 3;                         // row within chunk
  const int cg = (tid & 7) ^ (rc & 7);             // logical source granule
  const u16* baseA = A + (size_t)(m0 + rc) * lda + cg * 8;
  const u16* baseB = Bt + (size_t)(n0 + rc) * ldb + cg * 8;
  u16* ldsA = &sA[0][0] + rc * 64 + (tid & 7) * 8; // linear physical dest
  u16* ldsB = &sB[0][0] + rc * 64 + (tid & 7) * 8;

  // per-thread-constant read swizzle: row&7 == r15&7 for all fragment rows
  const int sw = r15 & 7;
  const int g0 = (hi ^ sw) * 8;        // kstep 0 granule offset (u16 units)
  const int g1 = ((4 + hi) ^ sw) * 8;  // kstep 1
  const int awrow = wm * 128 + r15;
  const int bwrow = wn * 64 + r15;
  const u16* sA0 = &sA[0][0]; const u16* sA1 = &sA[1][0];
  const u16* sB0 = &sB[0][0]; const u16* sB1 = &sB[1][0];

  f32x4 acc[8][4] = {};
  bf16x8 aE[8], aO[8], b[8];

  // ---- prologue: T0 -> buf0 (8 chunks), T1 -> buf1 (6 of 8 chunks) ----
  STG_A(0, 0, 0); STG_A(0, 64, 0); STG_A(0, 128, 0); STG_A(0, 192, 0);
  STG_B(0, 0, 0); STG_B(0, 64, 0); STG_B(0, 128, 0); STG_B(0, 192, 0);
  STG_A(1, 0, 1); STG_A(1, 128, 1);
  STG_B(1, 0, 1); STG_B(1, 64, 1); STG_B(1, 128, 1); STG_B(1, 192, 1);
  asm volatile("s_waitcnt vmcnt(6)" ::: "memory");
  __builtin_amdgcn_sched_barrier(0);
  __builtin_amdgcn_s_barrier();
  // pre-read T0.A0 + T0.B01 (drained at P1's lgkmcnt(0))
  RD_A(sA0, 0, aE); RD_BH(sB0, 0);

  int kb = 0;
  auto iter = [&](auto lastc) {
    constexpr bool L = decltype(lastc)::value;
    const int kO = kb + 1, k2 = kb + 2, k3 = kb + 3;
    // P1: MM(0,0)=aE*b01; window: T0.B23; stage T1.A64/A192 (always)
    PH_BEGIN();
    RD_BH(sB0, 1);
    MMQ(0, 0, aE);
    PH_END();
    STG_A(1, 64, kO); STG_A(1, 192, kO);
    // P2: MM(0,1)=aE*b23; window: T0.A1 -> aO; stage T2.A0/A128
    PH_BEGIN();
    RD_A(sA0, 1, aO);
    MMQ(0, 1, aE);
    PH_END();
    if constexpr (!L) { STG_A(0, 0, k2); STG_A(0, 128, k2); }
    // P3: MM(1,0)=aO*b01; no window reads; stage T2.B0/B64; GATE buf1
    PH_BEGIN();
    MMQ(1, 0, aO);
    PH_END();
    if constexpr (!L) { STG_B(0, 0, k2); STG_B(0, 64, k2); GATE4(); }
    else              { GATE0(); }
    // P4: MM(1,1)=aO*b23; window: T1.A0 -> aE, T1.B01; stage T2.B128/B192
    PH_BEGIN();
    RD_A(sA1, 0, aE); RD_BH(sB1, 0);
    MMQ(1, 1, aO);
    PH_END();
    if constexpr (!L) { STG_B(0, 128, k2); STG_B(0, 192, k2); }
    // P5: MM(0,0)=aE*b01 (T1); window: T1.B23; stage T2.A64/A192
    PH_BEGIN();
    RD_BH(sB1, 1);
    MMQ(0, 0, aE);
    PH_END();
    if constexpr (!L) { STG_A(0, 64, k2); STG_A(0, 192, k2); }
    // P6: MM(0,1); window: T1.A1 -> aO; stage T3.A0/A128
    PH_BEGIN();
    RD_A(sA1, 1, aO);
    MMQ(0, 1, aE);
    PH_END();
    if constexpr (!L) { STG_A(1, 0, k3); STG_A(1, 128, k3); }
    // P7: MM(1,0); no window reads; stage T3.B0/B64; GATE buf0
    PH_BEGIN();
    MMQ(1, 0, aO);
    PH_END();
    if constexpr (!L) { STG_B(1, 0, k3); STG_B(1, 64, k3); GATE4(); }
    else              { GATE0(); }
    // P8: MM(1,1); window: T2.A0 -> aE, T2.B01; stage T3.B128/B192
    PH_BEGIN();
    if constexpr (!L) { RD_A(sA0, 0, aE); RD_BH(sB0, 0); }
    MMQ(1, 1, aO);
    PH_END();
    if constexpr (!L) { STG_B(1, 128, k3); STG_B(1, 192, k3); }
    kb += 2;
  };
  for (int i = 0; i < NITER - 1; ++i) iter(FalseT{});
  iter(TrueT{});

  // ---- epilogue ----
  if constexpr (WRITEV) {
    if (n0 >= 2 * kDM) {  // V third: write transposed+permuted into Vt
      const int hswap = ((hi & 1) << 1) | (hi >> 1);  // bits2<->3 of (s&15), /4
#pragma unroll
      for (int im = 0; im < 8; ++im) {
        const int m_base = m0 + wm * 128 + im * 16;   // 16-aligned
        const int bq = m_base >> 11;                  // batch
        const int sp = (m_base & (kS - 1)) + hswap * 4;
#pragma unroll
        for (int in = 0; in < 4; ++in) {
          const int c = n0 - 2 * kDM + wn * 64 + in * 16 + r15;
          const int hh = c >> 7, dd = c & 127;
          u16* dst = Vt + ((size_t)((bq * kH + hh) * kDK + dd)) * kS + sp;
          ushort4 pk;
          pk.x = f2bf(acc[im][in][0]); pk.y = f2bf(acc[im][in][1]);
          pk.z = f2bf(acc[im][in][2]); pk.w = f2bf(acc[im][in][3]);
          *reinterpret_cast<ushort4*>(dst) = pk;      // one 8B store
        }
      }
      return;
    }
  }
  const size_t crow0 = (size_t)(m0 + wm * 128 + hi * 4);
  const int col0 = n0 + wn * 64 + r15;
#pragma unroll
  for (int im = 0; im < 8; ++im)
#pragma unroll
    for (int in = 0; in < 4; ++in)
#pragma unroll
      for (int r = 0; r < 4; ++r)
        cstore(&C[(crow0 + im * 16 + r) * ldc + col0 + in * 16], acc[im][in][r]);
}

// ------- flash attention: 4 waves x QBLK=64, KVBLK=64 staged / 32-k subtiles ----
// Two q-halves per wave. Per 32-k subtile: half-A QK+softmax (s f32x16 freed
// before half-B), half-B likewise, then ONE shared PV (each V ds_read feeds
// both halves). Peak live regs ~234 < 256 cap (R11's ~255 spilled).
// Grid 8x16x4 = 512 blocks = 2/CU, one co-resident round.
#define QKSM_ST(QF, O, MI, LI, PA, ST)                                     \
  do {                                                                     \
    f32x16 s_ = {};                                                        \
    _Pragma("unroll")                                                      \
    for (int ds = 0; ds < 8; ++ds) {                                       \
      int slot_ = ((ds * 2 + hi5) ^ (l31 & 7)) * 8;                        \
      bf16x8 kf_ = lds_frag(&Kb[((ST) * 32 + l31) * 128 + slot_]);         \
      s_ = __builtin_amdgcn_mfma_f32_32x32x16_bf16(kf_, QF[ds], s_, 0, 0, 0); \
    }                                                                      \
    float mx_ = s_[0];                                                     \
    _Pragma("unroll") for (int r = 1; r < 16; ++r) mx_ = fmaxf(mx_, s_[r]); \
    mx_ = fmaxf(mx_, __shfl_xor(mx_, 32));                                 \
    float mc_ = mx_ * kE2;                                                 \
    if (__any(mc_ > MI + 8.0f)) {                                          \
      float mn_ = fmaxf(MI, mc_);                                          \
      float corr_ = exp2_fast(MI - mn_);                                   \
      MI = mn_; LI *= corr_;                                               \
      _Pragma("unroll") for (int r = 0; r < 16; ++r) {                     \
        float c_ = __shfl(corr_, (r & 3) + 8 * (r >> 2) + 4 * hi5);        \
        O[0][r] *= c_; O[1][r] *= c_; O[2][r] *= c_; O[3][r] *= c_;        \
      }                                                                    \
    }                                                                      \
    float rs_ = 0.f;                                                       \
    u16x8 pw0_, pw1_;                                                      \
    _Pragma("unroll") for (int r = 0; r < 8; ++r) {                        \
      float pa_ = exp2_fast(s_[r] * kE2 - MI);                             \
      float pb_ = exp2_fast(s_[r + 8] * kE2 - MI);                         \
      rs_ += pa_ + pb_;                                                    \
      pw0_[r] = f2bf(pa_); pw1_[r] = f2bf(pb_);                            \
    }                                                                      \
    rs_ += __shfl_xor(rs_, 32);                                            \
    LI += rs_;                                                             \
    PA[0] = __builtin_bit_cast(bf16x8, pw0_);                              \
    PA[1] = __builtin_bit_cast(bf16x8, pw1_);                              \
  } while (0)

__global__ __launch_bounds__(256, 2) void attn_kernel(const u16* __restrict__ qkv,
    const u16* __restrict__ vt, u16* __restrict__ attn_out) {
  __shared__ __align__(16) u16 lds[2][16384];
  const int tid = threadIdx.x;
  const int lane = tid & 63, wid = tid >> 6;
  const int l31 = lane & 31, hi5 = lane >> 5;
  const int q0 = blockIdx.x * 256, h = blockIdx.y, b = blockIdx.z;
  const int bh = b * kH + h;

  const int krow = tid >> 4, kg = tid & 15;
  const u16* kp = qkv + (size_t)(b * kS + krow) * kNQKV + kDM + h * kDK
                  + (size_t)((kg ^ (krow & 7)) * 8);
  const int vrow = tid >> 3, vg = tid & 7;
  const u16* vp = vt + (size_t)(bh * kDK + vrow) * kS + (size_t)((vg ^ (vrow & 7)) * 8);

  auto stage_kv = [&](u16* dst) {
#pragma unroll
    for (int i = 0; i < 4; ++i)
      GLOAD16(kp + (size_t)i * 16 * kNQKV, dst + (tid + 256 * i) * 8);
#pragma unroll
    for (int i = 0; i < 4; ++i)
      GLOAD16(vp + (size_t)i * 32 * kS, dst + 8192 + (tid + 256 * i) * 8);
    kp += (size_t)64 * kNQKV;
    vp += 64;
  };

  // Q fragments straight from global for both halves (named arrays, const idx)
  bf16x8 qfA[8], qfB[8];
  {
    const u16* qa = qkv + (size_t)(b * kS + q0 + wid * 64 + l31) * kNQKV
                    + h * kDK + hi5 * 8;
    const u16* qb = qa + (size_t)32 * kNQKV;
#pragma unroll
    for (int ds = 0; ds < 8; ++ds) {
      qfA[ds] = *reinterpret_cast<const bf16x8*>(qa + ds * 16);
      qfB[ds] = *reinterpret_cast<const bf16x8*>(qb + ds * 16);
    }
  }
  stage_kv(lds[0]);
  __syncthreads();

  f32x16 oA[4] = {}, oB[4] = {};
  float miA = -1e30f, liA = 0.f, miB = -1e30f, liB = 0.f;
  int cur = 0;

  for (int t = 0; t < kS / 64; ++t) {
    if (t < kS / 64 - 1) stage_kv(lds[cur ^ 1]);

    const u16* Kb = (const u16*)lds[cur];
    const u16* Vb = Kb + 8192;

#pragma unroll
    for (int st = 0; st < 2; ++st) {
      bf16x8 paA[2], paB[2];
      QKSM_ST(qfA, oA, miA, liA, paA, st);
      QKSM_ST(qfB, oB, miB, liB, paB, st);

      // shared PV over this subtile's 32 k (global k-slices st*2 .. st*2+1)
#pragma unroll
      for (int dt = 0; dt < 4; ++dt) {
        const int row = dt * 32 + l31;
        const int rs8 = row & 7;
#pragma unroll
        for (int ks = 0; ks < 2; ++ks) {
          bf16x8 bv = lds_frag(&Vb[row * 64 + (((st * 2 + ks) * 2 + hi5) ^ rs8) * 8]);
          oA[dt] = __builtin_amdgcn_mfma_f32_32x32x16_bf16(paA[ks], bv, oA[dt], 0, 0, 0);
          oB[dt] = __builtin_amdgcn_mfma_f32_32x32x16_bf16(paB[ks], bv, oB[dt], 0, 0, 0);
        }
      }
    }

    __syncthreads();
    cur ^= 1;
  }

  // ---- epilogue: normalize, store bf16 [row q][col h*128+d] ----
  const size_t obase = (size_t)(b * kS + q0 + wid * 64) * kDM + h * kDK + l31;
  float rliA = 1.0f / liA, rliB = 1.0f / liB;
#pragma unroll
  for (int r = 0; r < 16; ++r) {
    int ql = (r & 3) + 8 * (r >> 2) + 4 * hi5;
    float wA = __shfl(rliA, ql);
    float wB = __shfl(rliB, ql);
#pragma unroll
    for (int dt = 0; dt < 4; ++dt) {
      attn_out[obase + (size_t)ql * kDM + dt * 32] = f2bf(oA[dt][r] * wA);
      attn_out[obase + (size_t)(32 + ql) * kDM + dt * 32] = f2bf(oB[dt][r] * wB);
    }
  }
}

// ---------------------------------------------------------------------------
extern "C" void kernel_launch(void* const* d_in, const int* in_sizes, int n_in,
                              void* d_out, int out_size, void* d_ws, size_t ws_size,
                              hipStream_t stream) {
  (void)in_sizes; (void)n_in; (void)out_size; (void)ws_size;
  const float* x  = (const float*)d_in[0];
  const float* wq = (const float*)d_in[1];
  const float* wk = (const float*)d_in[2];
  const float* wv = (const float*)d_in[3];
  const float* wo = (const float*)d_in[4];

  char* p = (char*)d_ws;
  u16* xb   = (u16*)p; p += (size_t)kM * kDM * 2;
  u16* wtc  = (u16*)p; p += (size_t)kNQKV * kDM * 2;
  u16* wot  = (u16*)p; p += (size_t)kDM * kDM * 2;
  u16* qkvb = (u16*)p; p += (size_t)kM * kNQKV * 2;
  u16* vtb  = (u16*)p; p += (size_t)kB * kH * kDK * kS * 2;
  u16* aob  = xb;  // reuse: x_bf16 dead after QKV gemm

  int n4 = kM * kDM / 4;
  cast_x_kernel<<<(n4 + 255) / 256, 256, 0, stream>>>(x, xb, n4);
  transpose_w_kernel<<<dim3(kDM / 32, kDM / 32, 4), dim3(32, 8), 0, stream>>>(
      wq, wk, wv, wo, wtc, wot);
  gemm256_kernel<u16, true><<<dim3(kNQKV / 256, kM / 256), 512, 0, stream>>>(
      xb, wtc, qkvb, vtb, kDM, kDM, kDM, kNQKV);
  attn_kernel<<<dim3(kS / 256, kH, kB), 256, 0, stream>>>(qkvb, vtb, aob);
  gemm256_kernel<float, false><<<dim3(kDM / 256, kM / 256), 512, 0, stream>>>(
      aob, wot, (float*)d_out, nullptr, kDM, kDM, kDM, kDM);
}

// Round 13
// 446.532 us; speedup vs baseline: 1.8420x; 1.0738x over previous
//
#include <hip/hip_runtime.h>
#include <hip/hip_bf16.h>

typedef __attribute__((ext_vector_type(8))) __bf16 bf16x8;
typedef __attribute__((ext_vector_type(4))) float f32x4;
typedef __attribute__((ext_vector_type(16))) float f32x16;
typedef __attribute__((ext_vector_type(8))) unsigned short u16x8;
typedef unsigned short u16;

#define DEVINL static __device__ __forceinline__

namespace {
constexpr int kB = 4;
constexpr int kS = 2048;
constexpr int kDM = 2048;
constexpr int kH = 16;
constexpr int kDK = 128;
constexpr int kM = kB * kS;        // 8192
constexpr int kNQKV = 3 * kDM;     // 6144
constexpr float kE2 = 0.08838834764831845f * 1.44269504088896f; // scale*log2(e)
}

DEVINL u16 f2bf(float f) {
  __hip_bfloat16 h = __float2bfloat16(f);
  return __builtin_bit_cast(u16, h);
}

#if __has_builtin(__builtin_amdgcn_exp2f)
DEVINL float exp2_fast(float x) { return __builtin_amdgcn_exp2f(x); }
#else
DEVINL float exp2_fast(float x) { return exp2f(x); }
#endif

#define GLOAD16(gp, lp) \
  __builtin_amdgcn_global_load_lds((const __attribute__((address_space(1))) void*)(gp), \
                                   (__attribute__((address_space(3))) void*)(lp), 16, 0, 0)

DEVINL bf16x8 lds_frag(const u16* p) { return *reinterpret_cast<const bf16x8*>(p); }

DEVINL f32x4 MFMA16x16(bf16x8 a, bf16x8 b, f32x4 c) {
  return __builtin_amdgcn_mfma_f32_16x16x32_bf16(a, b, c, 0, 0, 0);
}

struct TrueT { static constexpr bool value = true; };
struct FalseT { static constexpr bool value = false; };

// ---------------- cast x: fp32 -> bf16, x4 vectorized ----------------
__global__ __launch_bounds__(256) void cast_x_kernel(const float* __restrict__ x,
                                                     u16* __restrict__ o, int n4) {
  int i = blockIdx.x * 256 + threadIdx.x;
  if (i >= n4) return;
  float4 v = reinterpret_cast<const float4*>(x)[i];
  ushort4 r;
  r.x = f2bf(v.x); r.y = f2bf(v.y); r.z = f2bf(v.z); r.w = f2bf(v.w);
  reinterpret_cast<ushort4*>(o)[i] = r;
}

// ------------- transpose + cast weights: w[k][n] fp32 -> wt[n][k] bf16 -------------
__global__ __launch_bounds__(256) void transpose_w_kernel(const float* __restrict__ w0,
    const float* __restrict__ w1, const float* __restrict__ w2, const float* __restrict__ w3,
    u16* __restrict__ wtcat, u16* __restrict__ wot) {
  const float* src = (blockIdx.z == 0) ? w0 : (blockIdx.z == 1) ? w1
                    : (blockIdx.z == 2) ? w2 : w3;
  u16* dst = (blockIdx.z < 3) ? (wtcat + (size_t)blockIdx.z * kDM * kDM) : wot;
  __shared__ float tile[32][33];
  int n0 = blockIdx.x * 32, k0 = blockIdx.y * 32;
  int tx = threadIdx.x, ty = threadIdx.y;
#pragma unroll
  for (int i = 0; i < 4; ++i)
    tile[ty + i * 8][tx] = src[(size_t)(k0 + ty + i * 8) * kDM + n0 + tx];
  __syncthreads();
#pragma unroll
  for (int i = 0; i < 4; ++i)
    dst[(size_t)(n0 + ty + i * 8) * kDM + k0 + tx] = f2bf(tile[tx][ty + i * 8]);
}

// ===================== 256x256 8-phase GEMM (Bt layout), 16x16x32 MFMA ======
// Single barrier per phase (R9). Stage slotting R5; gates vmcnt(4) at P3/P7.
DEVINL void cstore(float* p, float v) { *p = v; }
DEVINL void cstore(u16* p, float v) { *p = f2bf(v); }

#define PH_BEGIN()                                     \
  __builtin_amdgcn_sched_barrier(0);                   \
  __builtin_amdgcn_s_barrier();                        \
  asm volatile("s_waitcnt lgkmcnt(0)" ::: "memory");   \
  __builtin_amdgcn_sched_barrier(0);                   \
  __builtin_amdgcn_s_setprio(1)

#define PH_END()                                       \
  __builtin_amdgcn_s_setprio(0);                       \
  __builtin_amdgcn_sched_barrier(0)

#define GATE4() \
  asm volatile("s_waitcnt vmcnt(4)" ::: "memory");     \
  __builtin_amdgcn_sched_barrier(0)

#define GATE0() \
  asm volatile("s_waitcnt vmcnt(0)" ::: "memory");     \
  __builtin_amdgcn_sched_barrier(0)

// read A-half MQ of tile buffer SB into DST[0..7]
#define RD_A(SB, MQ, DST)                                             \
  do {                                                                \
    _Pragma("unroll") for (int mf = 0; mf < 4; ++mf) {                \
      const u16* p_ = (SB) + (awrow + (MQ) * 64 + mf * 16) * 64;      \
      DST[mf * 2 + 0] = lds_frag(p_ + g0);                            \
      DST[mf * 2 + 1] = lds_frag(p_ + g1);                            \
    }                                                                 \
  } while (0)

// read B-half NH of tile buffer SB into b[NH*4 .. NH*4+3]
#define RD_BH(SB, NH)                                                 \
  do {                                                                \
    _Pragma("unroll") for (int nf = 0; nf < 2; ++nf) {                \
      const u16* p_ = (SB) + (bwrow + (NH) * 32 + nf * 16) * 64;      \
      b[(NH) * 4 + nf * 2 + 0] = lds_frag(p_ + g0);                   \
      b[(NH) * 4 + nf * 2 + 1] = lds_frag(p_ + g1);                   \
    }                                                                 \
  } while (0)

#define MMQ(MQ, NH, AF)                                               \
  do {                                                                \
    _Pragma("unroll") for (int mf = 0; mf < 4; ++mf)                  \
      _Pragma("unroll") for (int nf = 0; nf < 2; ++nf) {              \
        f32x4 t_ = acc[(MQ) * 4 + mf][(NH) * 2 + nf];                 \
        t_ = MFMA16x16(AF[mf * 2 + 0], b[(NH) * 4 + nf * 2 + 0], t_); \
        t_ = MFMA16x16(AF[mf * 2 + 1], b[(NH) * 4 + nf * 2 + 1], t_); \
        acc[(MQ) * 4 + mf][(NH) * 2 + nf] = t_;                       \
      }                                                               \
  } while (0)

#define STG_A(buf, R0, kt) \
  GLOAD16(baseA + (size_t)(R0) * lda + (size_t)(kt) * 64, ldsA + (buf) * 16384 + (R0) * 64)
#define STG_B(buf, R0, kt) \
  GLOAD16(baseB + (size_t)(R0) * ldb + (size_t)(kt) * 64, ldsB + (buf) * 16384 + (R0) * 64)

template <typename CT, bool WRITEV>
__global__ __launch_bounds__(512, 2) void gemm256_kernel(const u16* __restrict__ A,
    const u16* __restrict__ Bt, CT* __restrict__ C, u16* __restrict__ Vt,
    int K, int lda, int ldb, int ldc) {
  __shared__ __align__(16) u16 sA[2][16384];
  __shared__ __align__(16) u16 sB[2][16384];
  const int tid = threadIdx.x;
  const int lane = tid & 63, wid = tid >> 6;
  const int r15 = lane & 15, hi = lane >> 4;
  const int wm = wid >> 2, wn = wid & 3;

  // XCD-aware bijective swizzle (nwg % 8 == 0 for both launches)
  const int gx = gridDim.x, nwg = gx * gridDim.y;
  const int orig = blockIdx.y * gx + blockIdx.x;
  const int wg = (orig & 7) * (nwg >> 3) + (orig >> 3);
  const int n0 = (wg % gx) * 256;
  const int m0 = (wg / gx) * 256;

  const int NT = K >> 6;       // 64-wide k tiles (even)
  const int NITER = NT >> 1;

  // staging: thread stages 1 granule (16B) per 64-row chunk
  const int rc = tid >> 3;                         // row within chunk
  const int cg = (tid & 7) ^ (rc & 7);             // logical source granule
  const u16* baseA = A + (size_t)(m0 + rc) * lda + cg * 8;
  const u16* baseB = Bt + (size_t)(n0 + rc) * ldb + cg * 8;
  u16* ldsA = &sA[0][0] + rc * 64 + (tid & 7) * 8; // linear physical dest
  u16* ldsB = &sB[0][0] + rc * 64 + (tid & 7) * 8;

  // per-thread-constant read swizzle: row&7 == r15&7 for all fragment rows
  const int sw = r15 & 7;
  const int g0 = (hi ^ sw) * 8;        // kstep 0 granule offset (u16 units)
  const int g1 = ((4 + hi) ^ sw) * 8;  // kstep 1
  const int awrow = wm * 128 + r15;
  const int bwrow = wn * 64 + r15;
  const u16* sA0 = &sA[0][0]; const u16* sA1 = &sA[1][0];
  const u16* sB0 = &sB[0][0]; const u16* sB1 = &sB[1][0];

  f32x4 acc[8][4] = {};
  bf16x8 aE[8], aO[8], b[8];

  // ---- prologue: T0 -> buf0 (8 chunks), T1 -> buf1 (6 of 8 chunks) ----
  STG_A(0, 0, 0); STG_A(0, 64, 0); STG_A(0, 128, 0); STG_A(0, 192, 0);
  STG_B(0, 0, 0); STG_B(0, 64, 0); STG_B(0, 128, 0); STG_B(0, 192, 0);
  STG_A(1, 0, 1); STG_A(1, 128, 1);
  STG_B(1, 0, 1); STG_B(1, 64, 1); STG_B(1, 128, 1); STG_B(1, 192, 1);
  asm volatile("s_waitcnt vmcnt(6)" ::: "memory");
  __builtin_amdgcn_sched_barrier(0);
  __builtin_amdgcn_s_barrier();
  // pre-read T0.A0 + T0.B01 (drained at P1's lgkmcnt(0))
  RD_A(sA0, 0, aE); RD_BH(sB0, 0);

  int kb = 0;
  auto iter = [&](auto lastc) {
    constexpr bool L = decltype(lastc)::value;
    const int kO = kb + 1, k2 = kb + 2, k3 = kb + 3;
    // P1: MM(0,0)=aE*b01; window: T0.B23; stage T1.A64/A192 (always)
    PH_BEGIN();
    RD_BH(sB0, 1);
    MMQ(0, 0, aE);
    PH_END();
    STG_A(1, 64, kO); STG_A(1, 192, kO);
    // P2: MM(0,1)=aE*b23; window: T0.A1 -> aO; stage T2.A0/A128
    PH_BEGIN();
    RD_A(sA0, 1, aO);
    MMQ(0, 1, aE);
    PH_END();
    if constexpr (!L) { STG_A(0, 0, k2); STG_A(0, 128, k2); }
    // P3: MM(1,0)=aO*b01; no window reads; stage T2.B0/B64; GATE buf1
    PH_BEGIN();
    MMQ(1, 0, aO);
    PH_END();
    if constexpr (!L) { STG_B(0, 0, k2); STG_B(0, 64, k2); GATE4(); }
    else              { GATE0(); }
    // P4: MM(1,1)=aO*b23; window: T1.A0 -> aE, T1.B01; stage T2.B128/B192
    PH_BEGIN();
    RD_A(sA1, 0, aE); RD_BH(sB1, 0);
    MMQ(1, 1, aO);
    PH_END();
    if constexpr (!L) { STG_B(0, 128, k2); STG_B(0, 192, k2); }
    // P5: MM(0,0)=aE*b01 (T1); window: T1.B23; stage T2.A64/A192
    PH_BEGIN();
    RD_BH(sB1, 1);
    MMQ(0, 0, aE);
    PH_END();
    if constexpr (!L) { STG_A(0, 64, k2); STG_A(0, 192, k2); }
    // P6: MM(0,1); window: T1.A1 -> aO; stage T3.A0/A128
    PH_BEGIN();
    RD_A(sA1, 1, aO);
    MMQ(0, 1, aE);
    PH_END();
    if constexpr (!L) { STG_A(1, 0, k3); STG_A(1, 128, k3); }
    // P7: MM(1,0); no window reads; stage T3.B0/B64; GATE buf0
    PH_BEGIN();
    MMQ(1, 0, aO);
    PH_END();
    if constexpr (!L) { STG_B(1, 0, k3); STG_B(1, 64, k3); GATE4(); }
    else              { GATE0(); }
    // P8: MM(1,1); window: T2.A0 -> aE, T2.B01; stage T3.B128/B192
    PH_BEGIN();
    if constexpr (!L) { RD_A(sA0, 0, aE); RD_BH(sB0, 0); }
    MMQ(1, 1, aO);
    PH_END();
    if constexpr (!L) { STG_B(1, 128, k3); STG_B(1, 192, k3); }
    kb += 2;
  };
  for (int i = 0; i < NITER - 1; ++i) iter(FalseT{});
  iter(TrueT{});

  // ---- epilogue ----
  if constexpr (WRITEV) {
    if (n0 >= 2 * kDM) {  // V third: write transposed+permuted into Vt
      const int hswap = ((hi & 1) << 1) | (hi >> 1);  // bits2<->3 of (s&15), /4
#pragma unroll
      for (int im = 0; im < 8; ++im) {
        const int m_base = m0 + wm * 128 + im * 16;   // 16-aligned
        const int bq = m_base >> 11;                  // batch
        const int sp = (m_base & (kS - 1)) + hswap * 4;
#pragma unroll
        for (int in = 0; in < 4; ++in) {
          const int c = n0 - 2 * kDM + wn * 64 + in * 16 + r15;
          const int hh = c >> 7, dd = c & 127;
          u16* dst = Vt + ((size_t)((bq * kH + hh) * kDK + dd)) * kS + sp;
          ushort4 pk;
          pk.x = f2bf(acc[im][in][0]); pk.y = f2bf(acc[im][in][1]);
          pk.z = f2bf(acc[im][in][2]); pk.w = f2bf(acc[im][in][3]);
          *reinterpret_cast<ushort4*>(dst) = pk;      // one 8B store
        }
      }
      return;
    }
  }
  const size_t crow0 = (size_t)(m0 + wm * 128 + hi * 4);
  const int col0 = n0 + wn * 64 + r15;
#pragma unroll
  for (int im = 0; im < 8; ++im)
#pragma unroll
    for (int in = 0; in < 4; ++in)
#pragma unroll
      for (int r = 0; r < 4; ++r)
        cstore(&C[(crow0 + im * 16 + r) * ldc + col0 + in * 16], acc[im][in][r]);
}

// ------- flash attention: 4 waves x QBLK=32 (128 q/block), KVBLK=64 ----
// R9 compute structure; LDS cut 64->48KB: K double-buffered (2x16KB) +
// V single buffer (16KB) with counted-vmcnt gates -> 3 blocks/CU
// (3 waves/SIMD, +50% latency hiding vs R9's 2).
// Per tile: issue V[t](4 gloads) then K[t+1](4); gate QK with vmcnt(8)
// (retires exactly K[t]); gate PV with vmcnt(4) (retires V[t], K[t+1]
// stays in flight); end-of-tile barrier protects vbuf/kb reuse.
__global__ __launch_bounds__(256, 3) void attn_kernel(const u16* __restrict__ qkv,
    const u16* __restrict__ vt, u16* __restrict__ attn_out) {
  __shared__ __align__(16) u16 ldsK[2][8192];   // K dbuf: [64][128] each, 16KB
  __shared__ __align__(16) u16 ldsV[8192];      // V single: [128][64], 16KB
  const int tid = threadIdx.x;
  const int lane = tid & 63, wid = tid >> 6;
  const int l31 = lane & 31, hi5 = lane >> 5;
  const int q0 = blockIdx.x * 128, h = blockIdx.y, b = blockIdx.z;
  const int bh = b * kH + h;

  const int krow = tid >> 4, kg = tid & 15;
  const u16* kp = qkv + (size_t)(b * kS + krow) * kNQKV + kDM + h * kDK
                  + (size_t)((kg ^ (krow & 7)) * 8);
  const int vrow = tid >> 3, vg = tid & 7;
  const u16* vp = vt + (size_t)(bh * kDK + vrow) * kS + (size_t)((vg ^ (vrow & 7)) * 8);

  auto stage_k = [&](u16* dst) {
#pragma unroll
    for (int i = 0; i < 4; ++i)
      GLOAD16(kp + (size_t)i * 16 * kNQKV, dst + (tid + 256 * i) * 8);
    kp += (size_t)64 * kNQKV;
  };
  auto stage_v = [&]() {
#pragma unroll
    for (int i = 0; i < 4; ++i)
      GLOAD16(vp + (size_t)i * 32 * kS, &ldsV[0] + (tid + 256 * i) * 8);
    vp += 64;
  };

  // ---- prologue: Q -> ldsK[0..1] (32KB contiguous), read to regs ----
#pragma unroll
  for (int i = 0; i < 8; ++i) {
    int row = (tid >> 4) + 16 * i;
    GLOAD16(qkv + (size_t)(b * kS + q0 + row) * kNQKV + h * kDK
                + (size_t)(((tid & 15) ^ (row & 7)) * 8),
            &ldsK[0][0] + (tid + 256 * i) * 8);
  }
  __syncthreads();   // drains vmcnt(0): Q resident

  bf16x8 qf[8];
  {
    const int qrow = wid * 32 + l31;
#pragma unroll
    for (int ds = 0; ds < 8; ++ds) {
      int slot = (ds * 2 + hi5) ^ (qrow & 7);
      qf[ds] = lds_frag(&ldsK[0][0] + qrow * 128 + slot * 8);
    }
  }
  __syncthreads();   // all Q reads done before K[0] overwrites
  stage_k(&ldsK[0][0]);   // K[0]

  f32x16 o[4] = {};
  float mi = -1e30f, li = 0.f;
  int cur = 0;

  for (int t = 0; t < kS / 64; ++t) {
    stage_v();                                     // V[t] -> ldsV
    if (t < kS / 64 - 1) stage_k(&ldsK[cur ^ 1][0]);  // K[t+1]

    // gate K[t]: outstanding = K[t](4 oldest) + V[t](4) [+ K[t+1](4)]
    if (t < kS / 64 - 1) { asm volatile("s_waitcnt vmcnt(8)" ::: "memory"); }
    else                 { asm volatile("s_waitcnt vmcnt(4)" ::: "memory"); }
    __builtin_amdgcn_sched_barrier(0);
    __builtin_amdgcn_s_barrier();

    const u16* Kb = &ldsK[cur][0];
    f32x16 s0 = {}, s1 = {};
    const int kr = l31;
#pragma unroll
    for (int ds = 0; ds < 8; ++ds) {
      int slot = ((ds * 2 + hi5) ^ (kr & 7)) * 8;
      bf16x8 k0 = lds_frag(&Kb[kr * 128 + slot]);
      bf16x8 k1 = lds_frag(&Kb[(32 + kr) * 128 + slot]);
      s0 = __builtin_amdgcn_mfma_f32_32x32x16_bf16(k0, qf[ds], s0, 0, 0, 0);
      s1 = __builtin_amdgcn_mfma_f32_32x32x16_bf16(k1, qf[ds], s1, 0, 0, 0);
    }

    float mx = s0[0];
#pragma unroll
    for (int r = 1; r < 16; ++r) mx = fmaxf(mx, s0[r]);
#pragma unroll
    for (int r = 0; r < 16; ++r) mx = fmaxf(mx, s1[r]);
    mx = fmaxf(mx, __shfl_xor(mx, 32));
    float mc = mx * kE2;
    if (__any(mc > mi + 8.0f)) {
      float mn = fmaxf(mi, mc);
      float corr = exp2_fast(mi - mn);
      mi = mn;
      li *= corr;
#pragma unroll
      for (int r = 0; r < 16; ++r) {
        float c = __shfl(corr, (r & 3) + 8 * (r >> 2) + 4 * hi5);
        o[0][r] *= c; o[1][r] *= c; o[2][r] *= c; o[3][r] *= c;
      }
    }
    float p0[16], p1[16];
    float rs = 0.f;
#pragma unroll
    for (int r = 0; r < 16; ++r) { p0[r] = exp2_fast(s0[r] * kE2 - mi); rs += p0[r]; }
#pragma unroll
    for (int r = 0; r < 16; ++r) { p1[r] = exp2_fast(s1[r] * kE2 - mi); rs += p1[r]; }
    rs += __shfl_xor(rs, 32);
    li += rs;

    u16x8 pw0, pw1, pw2, pw3;
#pragma unroll
    for (int r = 0; r < 8; ++r) {
      pw0[r] = f2bf(p0[r]);
      pw1[r] = f2bf(p0[r + 8]);
      pw2[r] = f2bf(p1[r]);
      pw3[r] = f2bf(p1[r + 8]);
    }
    bf16x8 pa[4] = {__builtin_bit_cast(bf16x8, pw0), __builtin_bit_cast(bf16x8, pw1),
                    __builtin_bit_cast(bf16x8, pw2), __builtin_bit_cast(bf16x8, pw3)};

    // gate V[t]: outstanding = V[t](4 oldest) [+ K[t+1](4)]
    if (t < kS / 64 - 1) { asm volatile("s_waitcnt vmcnt(4)" ::: "memory"); }
    else                 { asm volatile("s_waitcnt vmcnt(0)" ::: "memory"); }
    __builtin_amdgcn_sched_barrier(0);
    __builtin_amdgcn_s_barrier();

#pragma unroll
    for (int dt = 0; dt < 4; ++dt) {
      const int row = dt * 32 + l31;
      const int rs8 = row & 7;
#pragma unroll
      for (int ks = 0; ks < 4; ++ks) {
        bf16x8 bv = lds_frag(&ldsV[row * 64 + ((ks * 2 + hi5) ^ rs8) * 8]);
        o[dt] = __builtin_amdgcn_mfma_f32_32x32x16_bf16(pa[ks], bv, o[dt], 0, 0, 0);
      }
    }

    // end of tile: all PV reads consumed (lgkm drained by MFMA use)
    __builtin_amdgcn_sched_barrier(0);
    __builtin_amdgcn_s_barrier();
    cur ^= 1;
  }

  float rli = 1.0f / li;
  const size_t obase = (size_t)(b * kS + q0 + wid * 32) * kDM + h * kDK + l31;
#pragma unroll
  for (int r = 0; r < 16; ++r) {
    int ql = (r & 3) + 8 * (r >> 2) + 4 * hi5;
    float w = __shfl(rli, ql);
#pragma unroll
    for (int dt = 0; dt < 4; ++dt)
      attn_out[obase + (size_t)ql * kDM + dt * 32] = f2bf(o[dt][r] * w);
  }
}

// ---------------------------------------------------------------------------
extern "C" void kernel_launch(void* const* d_in, const int* in_sizes, int n_in,
                              void* d_out, int out_size, void* d_ws, size_t ws_size,
                              hipStream_t stream) {
  (void)in_sizes; (void)n_in; (void)out_size; (void)ws_size;
  const float* x  = (const float*)d_in[0];
  const float* wq = (const float*)d_in[1];
  const float* wk = (const float*)d_in[2];
  const float* wv = (const float*)d_in[3];
  const float* wo = (const float*)d_in[4];

  char* p = (char*)d_ws;
  u16* xb   = (u16*)p; p += (size_t)kM * kDM * 2;
  u16* wtc  = (u16*)p; p += (size_t)kNQKV * kDM * 2;
  u16* wot  = (u16*)p; p += (size_t)kDM * kDM * 2;
  u16* qkvb = (u16*)p; p += (size_t)kM * kNQKV * 2;
  u16* vtb  = (u16*)p; p += (size_t)kB * kH * kDK * kS * 2;
  u16* aob  = xb;  // reuse: x_bf16 dead after QKV gemm

  int n4 = kM * kDM / 4;
  cast_x_kernel<<<(n4 + 255) / 256, 256, 0, stream>>>(x, xb, n4);
  transpose_w_kernel<<<dim3(kDM / 32, kDM / 32, 4), dim3(32, 8), 0, stream>>>(
      wq, wk, wv, wo, wtc, wot);
  gemm256_kernel<u16, true><<<dim3(kNQKV / 256, kM / 256), 512, 0, stream>>>(
      xb, wtc, qkvb, vtb, kDM, kDM, kDM, kNQKV);
  attn_kernel<<<dim3(kS / 128, kH, kB), 256, 0, stream>>>(qkvb, vtb, aob);
  gemm256_kernel<float, false><<<dim3(kDM / 256, kM / 256), 512, 0, stream>>>(
      aob, wot, (float*)d_out, nullptr, kDM, kDM, kDM, kDM);
}

// Round 14
// 436.502 us; speedup vs baseline: 1.8843x; 1.0230x over previous
//
#include <hip/hip_runtime.h>
#include <hip/hip_bf16.h>

typedef __attribute__((ext_vector_type(8))) __bf16 bf16x8;
typedef __attribute__((ext_vector_type(4))) float f32x4;
typedef __attribute__((ext_vector_type(16))) float f32x16;
typedef __attribute__((ext_vector_type(8))) unsigned short u16x8;
typedef unsigned short u16;

#define DEVINL static __device__ __forceinline__

namespace {
constexpr int kB = 4;
constexpr int kS = 2048;
constexpr int kDM = 2048;
constexpr int kH = 16;
constexpr int kDK = 128;
constexpr int kM = kB * kS;        // 8192
constexpr int kNQKV = 3 * kDM;     // 6144
constexpr float kE2 = 0.08838834764831845f * 1.44269504088896f; // scale*log2(e)
}

DEVINL u16 f2bf(float f) {
  __hip_bfloat16 h = __float2bfloat16(f);
  return __builtin_bit_cast(u16, h);
}

#if __has_builtin(__builtin_amdgcn_exp2f)
DEVINL float exp2_fast(float x) { return __builtin_amdgcn_exp2f(x); }
#else
DEVINL float exp2_fast(float x) { return exp2f(x); }
#endif

#define GLOAD16(gp, lp) \
  __builtin_amdgcn_global_load_lds((const __attribute__((address_space(1))) void*)(gp), \
                                   (__attribute__((address_space(3))) void*)(lp), 16, 0, 0)

DEVINL bf16x8 lds_frag(const u16* p) { return *reinterpret_cast<const bf16x8*>(p); }

DEVINL f32x4 MFMA16x16(bf16x8 a, bf16x8 b, f32x4 c) {
  return __builtin_amdgcn_mfma_f32_16x16x32_bf16(a, b, c, 0, 0, 0);
}

struct TrueT { static constexpr bool value = true; };
struct FalseT { static constexpr bool value = false; };

// ---------------- cast x: fp32 -> bf16, x4 vectorized ----------------
__global__ __launch_bounds__(256) void cast_x_kernel(const float* __restrict__ x,
                                                     u16* __restrict__ o, int n4) {
  int i = blockIdx.x * 256 + threadIdx.x;
  if (i >= n4) return;
  float4 v = reinterpret_cast<const float4*>(x)[i];
  ushort4 r;
  r.x = f2bf(v.x); r.y = f2bf(v.y); r.z = f2bf(v.z); r.w = f2bf(v.w);
  reinterpret_cast<ushort4*>(o)[i] = r;
}

// ------------- transpose + cast weights: w[k][n] fp32 -> wt[n][k] bf16 -------------
__global__ __launch_bounds__(256) void transpose_w_kernel(const float* __restrict__ w0,
    const float* __restrict__ w1, const float* __restrict__ w2, const float* __restrict__ w3,
    u16* __restrict__ wtcat, u16* __restrict__ wot) {
  const float* src = (blockIdx.z == 0) ? w0 : (blockIdx.z == 1) ? w1
                    : (blockIdx.z == 2) ? w2 : w3;
  u16* dst = (blockIdx.z < 3) ? (wtcat + (size_t)blockIdx.z * kDM * kDM) : wot;
  __shared__ float tile[32][33];
  int n0 = blockIdx.x * 32, k0 = blockIdx.y * 32;
  int tx = threadIdx.x, ty = threadIdx.y;
#pragma unroll
  for (int i = 0; i < 4; ++i)
    tile[ty + i * 8][tx] = src[(size_t)(k0 + ty + i * 8) * kDM + n0 + tx];
  __syncthreads();
#pragma unroll
  for (int i = 0; i < 4; ++i)
    dst[(size_t)(n0 + ty + i * 8) * kDM + k0 + tx] = f2bf(tile[tx][ty + i * 8]);
}

// ===================== 256x256 8-phase GEMM (Bt layout), 16x16x32 MFMA ======
// Single barrier per phase (R9). Stage slotting R5; gates vmcnt(4) at P3/P7.
DEVINL void cstore(float* p, float v) { *p = v; }
DEVINL void cstore(u16* p, float v) { *p = f2bf(v); }

#define PH_BEGIN()                                     \
  __builtin_amdgcn_sched_barrier(0);                   \
  __builtin_amdgcn_s_barrier();                        \
  asm volatile("s_waitcnt lgkmcnt(0)" ::: "memory");   \
  __builtin_amdgcn_sched_barrier(0);                   \
  __builtin_amdgcn_s_setprio(1)

#define PH_END()                                       \
  __builtin_amdgcn_s_setprio(0);                       \
  __builtin_amdgcn_sched_barrier(0)

#define GATE4() \
  asm volatile("s_waitcnt vmcnt(4)" ::: "memory");     \
  __builtin_amdgcn_sched_barrier(0)

#define GATE0() \
  asm volatile("s_waitcnt vmcnt(0)" ::: "memory");     \
  __builtin_amdgcn_sched_barrier(0)

// read A-half MQ of tile buffer SB into DST[0..7]
#define RD_A(SB, MQ, DST)                                             \
  do {                                                                \
    _Pragma("unroll") for (int mf = 0; mf < 4; ++mf) {                \
      const u16* p_ = (SB) + (awrow + (MQ) * 64 + mf * 16) * 64;      \
      DST[mf * 2 + 0] = lds_frag(p_ + g0);                            \
      DST[mf * 2 + 1] = lds_frag(p_ + g1);                            \
    }                                                                 \
  } while (0)

// read B-half NH of tile buffer SB into b[NH*4 .. NH*4+3]
#define RD_BH(SB, NH)                                                 \
  do {                                                                \
    _Pragma("unroll") for (int nf = 0; nf < 2; ++nf) {                \
      const u16* p_ = (SB) + (bwrow + (NH) * 32 + nf * 16) * 64;      \
      b[(NH) * 4 + nf * 2 + 0] = lds_frag(p_ + g0);                   \
      b[(NH) * 4 + nf * 2 + 1] = lds_frag(p_ + g1);                   \
    }                                                                 \
  } while (0)

#define MMQ(MQ, NH, AF)                                               \
  do {                                                                \
    _Pragma("unroll") for (int mf = 0; mf < 4; ++mf)                  \
      _Pragma("unroll") for (int nf = 0; nf < 2; ++nf) {              \
        f32x4 t_ = acc[(MQ) * 4 + mf][(NH) * 2 + nf];                 \
        t_ = MFMA16x16(AF[mf * 2 + 0], b[(NH) * 4 + nf * 2 + 0], t_); \
        t_ = MFMA16x16(AF[mf * 2 + 1], b[(NH) * 4 + nf * 2 + 1], t_); \
        acc[(MQ) * 4 + mf][(NH) * 2 + nf] = t_;                       \
      }                                                               \
  } while (0)

#define STG_A(buf, R0, kt) \
  GLOAD16(baseA + (size_t)(R0) * lda + (size_t)(kt) * 64, ldsA + (buf) * 16384 + (R0) * 64)
#define STG_B(buf, R0, kt) \
  GLOAD16(baseB + (size_t)(R0) * ldb + (size_t)(kt) * 64, ldsB + (buf) * 16384 + (R0) * 64)

template <typename CT, bool WRITEV>
__global__ __launch_bounds__(512, 2) void gemm256_kernel(const u16* __restrict__ A,
    const u16* __restrict__ Bt, CT* __restrict__ C, u16* __restrict__ Vt,
    int K, int lda, int ldb, int ldc) {
  __shared__ __align__(16) u16 sA[2][16384];
  __shared__ __align__(16) u16 sB[2][16384];
  const int tid = threadIdx.x;
  const int lane = tid & 63, wid = tid >> 6;
  const int r15 = lane & 15, hi = lane >> 4;
  const int wm = wid >> 2, wn = wid & 3;

  // XCD-aware bijective swizzle (nwg % 8 == 0 for both launches)
  const int gx = gridDim.x, nwg = gx * gridDim.y;
  const int orig = blockIdx.y * gx + blockIdx.x;
  const int wg = (orig & 7) * (nwg >> 3) + (orig >> 3);
  const int n0 = (wg % gx) * 256;
  const int m0 = (wg / gx) * 256;

  const int NT = K >> 6;       // 64-wide k tiles (even)
  const int NITER = NT >> 1;

  // staging: thread stages 1 granule (16B) per 64-row chunk
  const int rc = tid >> 3;                         // row within chunk
  const int cg = (tid & 7) ^ (rc & 7);             // logical source granule
  const u16* baseA = A + (size_t)(m0 + rc) * lda + cg * 8;
  const u16* baseB = Bt + (size_t)(n0 + rc) * ldb + cg * 8;
  u16* ldsA = &sA[0][0] + rc * 64 + (tid & 7) * 8; // linear physical dest
  u16* ldsB = &sB[0][0] + rc * 64 + (tid & 7) * 8;

  // per-thread-constant read swizzle: row&7 == r15&7 for all fragment rows
  const int sw = r15 & 7;
  const int g0 = (hi ^ sw) * 8;        // kstep 0 granule offset (u16 units)
  const int g1 = ((4 + hi) ^ sw) * 8;  // kstep 1
  const int awrow = wm * 128 + r15;
  const int bwrow = wn * 64 + r15;
  const u16* sA0 = &sA[0][0]; const u16* sA1 = &sA[1][0];
  const u16* sB0 = &sB[0][0]; const u16* sB1 = &sB[1][0];

  f32x4 acc[8][4] = {};
  bf16x8 aE[8], aO[8], b[8];

  // ---- prologue: T0 -> buf0 (8 chunks), T1 -> buf1 (6 of 8 chunks) ----
  STG_A(0, 0, 0); STG_A(0, 64, 0); STG_A(0, 128, 0); STG_A(0, 192, 0);
  STG_B(0, 0, 0); STG_B(0, 64, 0); STG_B(0, 128, 0); STG_B(0, 192, 0);
  STG_A(1, 0, 1); STG_A(1, 128, 1);
  STG_B(1, 0, 1); STG_B(1, 64, 1); STG_B(1, 128, 1); STG_B(1, 192, 1);
  asm volatile("s_waitcnt vmcnt(6)" ::: "memory");
  __builtin_amdgcn_sched_barrier(0);
  __builtin_amdgcn_s_barrier();
  // pre-read T0.A0 + T0.B01 (drained at P1's lgkmcnt(0))
  RD_A(sA0, 0, aE); RD_BH(sB0, 0);

  int kb = 0;
  auto iter = [&](auto lastc) {
    constexpr bool L = decltype(lastc)::value;
    const int kO = kb + 1, k2 = kb + 2, k3 = kb + 3;
    // P1: MM(0,0)=aE*b01; window: T0.B23; stage T1.A64/A192 (always)
    PH_BEGIN();
    RD_BH(sB0, 1);
    MMQ(0, 0, aE);
    PH_END();
    STG_A(1, 64, kO); STG_A(1, 192, kO);
    // P2: MM(0,1)=aE*b23; window: T0.A1 -> aO; stage T2.A0/A128
    PH_BEGIN();
    RD_A(sA0, 1, aO);
    MMQ(0, 1, aE);
    PH_END();
    if constexpr (!L) { STG_A(0, 0, k2); STG_A(0, 128, k2); }
    // P3: MM(1,0)=aO*b01; no window reads; stage T2.B0/B64; GATE buf1
    PH_BEGIN();
    MMQ(1, 0, aO);
    PH_END();
    if constexpr (!L) { STG_B(0, 0, k2); STG_B(0, 64, k2); GATE4(); }
    else              { GATE0(); }
    // P4: MM(1,1)=aO*b23; window: T1.A0 -> aE, T1.B01; stage T2.B128/B192
    PH_BEGIN();
    RD_A(sA1, 0, aE); RD_BH(sB1, 0);
    MMQ(1, 1, aO);
    PH_END();
    if constexpr (!L) { STG_B(0, 128, k2); STG_B(0, 192, k2); }
    // P5: MM(0,0)=aE*b01 (T1); window: T1.B23; stage T2.A64/A192
    PH_BEGIN();
    RD_BH(sB1, 1);
    MMQ(0, 0, aE);
    PH_END();
    if constexpr (!L) { STG_A(0, 64, k2); STG_A(0, 192, k2); }
    // P6: MM(0,1); window: T1.A1 -> aO; stage T3.A0/A128
    PH_BEGIN();
    RD_A(sA1, 1, aO);
    MMQ(0, 1, aE);
    PH_END();
    if constexpr (!L) { STG_A(1, 0, k3); STG_A(1, 128, k3); }
    // P7: MM(1,0); no window reads; stage T3.B0/B64; GATE buf0
    PH_BEGIN();
    MMQ(1, 0, aO);
    PH_END();
    if constexpr (!L) { STG_B(1, 0, k3); STG_B(1, 64, k3); GATE4(); }
    else              { GATE0(); }
    // P8: MM(1,1); window: T2.A0 -> aE, T2.B01; stage T3.B128/B192
    PH_BEGIN();
    if constexpr (!L) { RD_A(sA0, 0, aE); RD_BH(sB0, 0); }
    MMQ(1, 1, aO);
    PH_END();
    if constexpr (!L) { STG_B(1, 128, k3); STG_B(1, 192, k3); }
    kb += 2;
  };
  for (int i = 0; i < NITER - 1; ++i) iter(FalseT{});
  iter(TrueT{});

  // ---- epilogue ----
  if constexpr (WRITEV) {
    if (n0 >= 2 * kDM) {  // V third: write transposed+permuted into Vt
      const int hswap = ((hi & 1) << 1) | (hi >> 1);  // bits2<->3 of (s&15), /4
#pragma unroll
      for (int im = 0; im < 8; ++im) {
        const int m_base = m0 + wm * 128 + im * 16;   // 16-aligned
        const int bq = m_base >> 11;                  // batch
        const int sp = (m_base & (kS - 1)) + hswap * 4;
#pragma unroll
        for (int in = 0; in < 4; ++in) {
          const int c = n0 - 2 * kDM + wn * 64 + in * 16 + r15;
          const int hh = c >> 7, dd = c & 127;
          u16* dst = Vt + ((size_t)((bq * kH + hh) * kDK + dd)) * kS + sp;
          ushort4 pk;
          pk.x = f2bf(acc[im][in][0]); pk.y = f2bf(acc[im][in][1]);
          pk.z = f2bf(acc[im][in][2]); pk.w = f2bf(acc[im][in][3]);
          *reinterpret_cast<ushort4*>(dst) = pk;      // one 8B store
        }
      }
      return;
    }
  }
  const size_t crow0 = (size_t)(m0 + wm * 128 + hi * 4);
  const int col0 = n0 + wn * 64 + r15;
#pragma unroll
  for (int im = 0; im < 8; ++im)
#pragma unroll
    for (int in = 0; in < 4; ++in)
#pragma unroll
      for (int r = 0; r < 4; ++r)
        cstore(&C[(crow0 + im * 16 + r) * ldc + col0 + in * 16], acc[im][in][r]);
}

// ------------- flash attention (R6/R9 proven version): 4 waves x QBLK=32 ----
// K/V double-buffered in LDS (64KB, 2 blocks/CU); Q staged once via lds[1]
// then registers. Vt pre-permuted so each PV B-fragment is one ds_read_b128.
// + T5: s_setprio(1) around the QK and PV MFMA clusters (two co-resident
// blocks are unsynchronized -> scheduler can favor the MFMA-phase wave).
__global__ __launch_bounds__(256, 2) void attn_kernel(const u16* __restrict__ qkv,
    const u16* __restrict__ vt, u16* __restrict__ attn_out) {
  __shared__ __align__(16) u16 lds[2][16384];
  const int tid = threadIdx.x;
  const int lane = tid & 63, wid = tid >> 6;
  const int l31 = lane & 31, hi5 = lane >> 5;
  const int q0 = blockIdx.x * 128, h = blockIdx.y, b = blockIdx.z;
  const int bh = b * kH + h;

  const int krow = tid >> 4, kg = tid & 15;
  const u16* kp = qkv + (size_t)(b * kS + krow) * kNQKV + kDM + h * kDK
                  + (size_t)((kg ^ (krow & 7)) * 8);
  const int vrow = tid >> 3, vg = tid & 7;
  const u16* vp = vt + (size_t)(bh * kDK + vrow) * kS + (size_t)((vg ^ (vrow & 7)) * 8);

  auto stage_kv = [&](u16* dst) {
#pragma unroll
    for (int i = 0; i < 4; ++i)
      GLOAD16(kp + (size_t)i * 16 * kNQKV, dst + (tid + 256 * i) * 8);
#pragma unroll
    for (int i = 0; i < 4; ++i)
      GLOAD16(vp + (size_t)i * 32 * kS, dst + 8192 + (tid + 256 * i) * 8);
    kp += (size_t)64 * kNQKV;
    vp += 64;
  };

#pragma unroll
  for (int i = 0; i < 8; ++i) {
    int row = (tid >> 4) + 16 * i;
    GLOAD16(qkv + (size_t)(b * kS + q0 + row) * kNQKV + h * kDK
                + (size_t)(((tid & 15) ^ (row & 7)) * 8),
            (u16*)lds[1] + (tid + 256 * i) * 8);
  }
  stage_kv(lds[0]);
  __syncthreads();

  bf16x8 qf[8];
  {
    const int qrow = wid * 32 + l31;
    const u16* qb = (const u16*)lds[1];
#pragma unroll
    for (int ds = 0; ds < 8; ++ds) {
      int slot = (ds * 2 + hi5) ^ (qrow & 7);
      qf[ds] = lds_frag(&qb[qrow * 128 + slot * 8]);
    }
  }
  __syncthreads();

  f32x16 o[4] = {};
  float mi = -1e30f, li = 0.f;
  int cur = 0;

  for (int t = 0; t < kS / 64; ++t) {
    if (t < kS / 64 - 1) stage_kv(lds[cur ^ 1]);

    const u16* Kb = (const u16*)lds[cur];
    const u16* Vb = Kb + 8192;

    f32x16 s0 = {}, s1 = {};
    const int kr = l31;
    __builtin_amdgcn_s_setprio(1);
#pragma unroll
    for (int ds = 0; ds < 8; ++ds) {
      int slot = ((ds * 2 + hi5) ^ (kr & 7)) * 8;
      bf16x8 k0 = lds_frag(&Kb[kr * 128 + slot]);
      bf16x8 k1 = lds_frag(&Kb[(32 + kr) * 128 + slot]);
      s0 = __builtin_amdgcn_mfma_f32_32x32x16_bf16(k0, qf[ds], s0, 0, 0, 0);
      s1 = __builtin_amdgcn_mfma_f32_32x32x16_bf16(k1, qf[ds], s1, 0, 0, 0);
    }
    __builtin_amdgcn_s_setprio(0);

    float mx = s0[0];
#pragma unroll
    for (int r = 1; r < 16; ++r) mx = fmaxf(mx, s0[r]);
#pragma unroll
    for (int r = 0; r < 16; ++r) mx = fmaxf(mx, s1[r]);
    mx = fmaxf(mx, __shfl_xor(mx, 32));
    float mc = mx * kE2;
    if (__any(mc > mi + 8.0f)) {
      float mn = fmaxf(mi, mc);
      float corr = exp2_fast(mi - mn);
      mi = mn;
      li *= corr;
#pragma unroll
      for (int r = 0; r < 16; ++r) {
        float c = __shfl(corr, (r & 3) + 8 * (r >> 2) + 4 * hi5);
        o[0][r] *= c; o[1][r] *= c; o[2][r] *= c; o[3][r] *= c;
      }
    }
    float p0[16], p1[16];
    float rs = 0.f;
#pragma unroll
    for (int r = 0; r < 16; ++r) { p0[r] = exp2_fast(s0[r] * kE2 - mi); rs += p0[r]; }
#pragma unroll
    for (int r = 0; r < 16; ++r) { p1[r] = exp2_fast(s1[r] * kE2 - mi); rs += p1[r]; }
    rs += __shfl_xor(rs, 32);
    li += rs;

    u16x8 pw0, pw1, pw2, pw3;
#pragma unroll
    for (int r = 0; r < 8; ++r) {
      pw0[r] = f2bf(p0[r]);
      pw1[r] = f2bf(p0[r + 8]);
      pw2[r] = f2bf(p1[r]);
      pw3[r] = f2bf(p1[r + 8]);
    }
    bf16x8 pa[4] = {__builtin_bit_cast(bf16x8, pw0), __builtin_bit_cast(bf16x8, pw1),
                    __builtin_bit_cast(bf16x8, pw2), __builtin_bit_cast(bf16x8, pw3)};

    __builtin_amdgcn_s_setprio(1);
#pragma unroll
    for (int dt = 0; dt < 4; ++dt) {
      const int row = dt * 32 + l31;
      const int rs8 = row & 7;
#pragma unroll
      for (int ks = 0; ks < 4; ++ks) {
        bf16x8 bv = lds_frag(&Vb[row * 64 + ((ks * 2 + hi5) ^ rs8) * 8]);
        o[dt] = __builtin_amdgcn_mfma_f32_32x32x16_bf16(pa[ks], bv, o[dt], 0, 0, 0);
      }
    }
    __builtin_amdgcn_s_setprio(0);

    __syncthreads();
    cur ^= 1;
  }

  float rli = 1.0f / li;
  const size_t obase = (size_t)(b * kS + q0 + wid * 32) * kDM + h * kDK + l31;
#pragma unroll
  for (int r = 0; r < 16; ++r) {
    int ql = (r & 3) + 8 * (r >> 2) + 4 * hi5;
    float w = __shfl(rli, ql);
#pragma unroll
    for (int dt = 0; dt < 4; ++dt)
      attn_out[obase + (size_t)ql * kDM + dt * 32] = f2bf(o[dt][r] * w);
  }
}

// ---------------------------------------------------------------------------
extern "C" void kernel_launch(void* const* d_in, const int* in_sizes, int n_in,
                              void* d_out, int out_size, void* d_ws, size_t ws_size,
                              hipStream_t stream) {
  (void)in_sizes; (void)n_in; (void)out_size; (void)ws_size;
  const float* x  = (const float*)d_in[0];
  const float* wq = (const float*)d_in[1];
  const float* wk = (const float*)d_in[2];
  const float* wv = (const float*)d_in[3];
  const float* wo = (const float*)d_in[4];

  char* p = (char*)d_ws;
  u16* xb   = (u16*)p; p += (size_t)kM * kDM * 2;
  u16* wtc  = (u16*)p; p += (size_t)kNQKV * kDM * 2;
  u16* wot  = (u16*)p; p += (size_t)kDM * kDM * 2;
  u16* qkvb = (u16*)p; p += (size_t)kM * kNQKV * 2;
  u16* vtb  = (u16*)p; p += (size_t)kB * kH * kDK * kS * 2;
  u16* aob  = xb;  // reuse: x_bf16 dead after QKV gemm

  int n4 = kM * kDM / 4;
  cast_x_kernel<<<(n4 + 255) / 256, 256, 0, stream>>>(x, xb, n4);
  transpose_w_kernel<<<dim3(kDM / 32, kDM / 32, 4), dim3(32, 8), 0, stream>>>(
      wq, wk, wv, wo, wtc, wot);
  gemm256_kernel<u16, true><<<dim3(kNQKV / 256, kM / 256), 512, 0, stream>>>(
      xb, wtc, qkvb, vtb, kDM, kDM, kDM, kNQKV);
  attn_kernel<<<dim3(kS / 128, kH, kB), 256, 0, stream>>>(qkvb, vtb, aob);
  gemm256_kernel<float, false><<<dim3(kDM / 256, kM / 256), 512, 0, stream>>>(
      aob, wot, (float*)d_out, nullptr, kDM, kDM, kDM, kDM);
}

// Round 15
// 425.892 us; speedup vs baseline: 1.9313x; 1.0249x over previous
//
#include <hip/hip_runtime.h>
#include <hip/hip_bf16.h>

typedef __attribute__((ext_vector_type(8))) __bf16 bf16x8;
typedef __attribute__((ext_vector_type(4))) float f32x4;
typedef __attribute__((ext_vector_type(16))) float f32x16;
typedef __attribute__((ext_vector_type(8))) unsigned short u16x8;
typedef unsigned short u16;

#define DEVINL static __device__ __forceinline__

namespace {
constexpr int kB = 4;
constexpr int kS = 2048;
constexpr int kDM = 2048;
constexpr int kH = 16;
constexpr int kDK = 128;
constexpr int kM = kB * kS;        // 8192
constexpr int kNQKV = 3 * kDM;     // 6144
constexpr float kE2 = 0.08838834764831845f * 1.44269504088896f; // scale*log2(e)
}

DEVINL u16 f2bf(float f) {
  __hip_bfloat16 h = __float2bfloat16(f);
  return __builtin_bit_cast(u16, h);
}

#if __has_builtin(__builtin_amdgcn_exp2f)
DEVINL float exp2_fast(float x) { return __builtin_amdgcn_exp2f(x); }
#else
DEVINL float exp2_fast(float x) { return exp2f(x); }
#endif

#define GLOAD16(gp, lp) \
  __builtin_amdgcn_global_load_lds((const __attribute__((address_space(1))) void*)(gp), \
                                   (__attribute__((address_space(3))) void*)(lp), 16, 0, 0)

DEVINL bf16x8 lds_frag(const u16* p) { return *reinterpret_cast<const bf16x8*>(p); }

DEVINL f32x4 MFMA16x16(bf16x8 a, bf16x8 b, f32x4 c) {
  return __builtin_amdgcn_mfma_f32_16x16x32_bf16(a, b, c, 0, 0, 0);
}

struct TrueT { static constexpr bool value = true; };
struct FalseT { static constexpr bool value = false; };

// ---------------- cast x: fp32 -> bf16, x4 vectorized ----------------
__global__ __launch_bounds__(256) void cast_x_kernel(const float* __restrict__ x,
                                                     u16* __restrict__ o, int n4) {
  int i = blockIdx.x * 256 + threadIdx.x;
  if (i >= n4) return;
  float4 v = reinterpret_cast<const float4*>(x)[i];
  ushort4 r;
  r.x = f2bf(v.x); r.y = f2bf(v.y); r.z = f2bf(v.z); r.w = f2bf(v.w);
  reinterpret_cast<ushort4*>(o)[i] = r;
}

// ------------- transpose + cast weights: w[k][n] fp32 -> wt[n][k] bf16 -------------
__global__ __launch_bounds__(256) void transpose_w_kernel(const float* __restrict__ w0,
    const float* __restrict__ w1, const float* __restrict__ w2, const float* __restrict__ w3,
    u16* __restrict__ wtcat, u16* __restrict__ wot) {
  const float* src = (blockIdx.z == 0) ? w0 : (blockIdx.z == 1) ? w1
                    : (blockIdx.z == 2) ? w2 : w3;
  u16* dst = (blockIdx.z < 3) ? (wtcat + (size_t)blockIdx.z * kDM * kDM) : wot;
  __shared__ float tile[32][33];
  int n0 = blockIdx.x * 32, k0 = blockIdx.y * 32;
  int tx = threadIdx.x, ty = threadIdx.y;
#pragma unroll
  for (int i = 0; i < 4; ++i)
    tile[ty + i * 8][tx] = src[(size_t)(k0 + ty + i * 8) * kDM + n0 + tx];
  __syncthreads();
#pragma unroll
  for (int i = 0; i < 4; ++i)
    dst[(size_t)(n0 + ty + i * 8) * kDM + k0 + tx] = f2bf(tile[tx][ty + i * 8]);
}

// ===================== 256x256 8-phase GEMM (Bt layout), 16x16x32 MFMA ======
// Single barrier per phase (R9). Stage slotting R5; gates vmcnt(4) at P3/P7.
DEVINL void cstore(float* p, float v) { *p = v; }
DEVINL void cstore(u16* p, float v) { *p = f2bf(v); }

#define PH_BEGIN()                                     \
  __builtin_amdgcn_sched_barrier(0);                   \
  __builtin_amdgcn_s_barrier();                        \
  asm volatile("s_waitcnt lgkmcnt(0)" ::: "memory");   \
  __builtin_amdgcn_sched_barrier(0);                   \
  __builtin_amdgcn_s_setprio(1)

#define PH_END()                                       \
  __builtin_amdgcn_s_setprio(0);                       \
  __builtin_amdgcn_sched_barrier(0)

#define GATE4() \
  asm volatile("s_waitcnt vmcnt(4)" ::: "memory");     \
  __builtin_amdgcn_sched_barrier(0)

#define GATE0() \
  asm volatile("s_waitcnt vmcnt(0)" ::: "memory");     \
  __builtin_amdgcn_sched_barrier(0)

// read A-half MQ of tile buffer SB into DST[0..7]
#define RD_A(SB, MQ, DST)                                             \
  do {                                                                \
    _Pragma("unroll") for (int mf = 0; mf < 4; ++mf) {                \
      const u16* p_ = (SB) + (awrow + (MQ) * 64 + mf * 16) * 64;      \
      DST[mf * 2 + 0] = lds_frag(p_ + g0);                            \
      DST[mf * 2 + 1] = lds_frag(p_ + g1);                            \
    }                                                                 \
  } while (0)

// read B-half NH of tile buffer SB into b[NH*4 .. NH*4+3]
#define RD_BH(SB, NH)                                                 \
  do {                                                                \
    _Pragma("unroll") for (int nf = 0; nf < 2; ++nf) {                \
      const u16* p_ = (SB) + (bwrow + (NH) * 32 + nf * 16) * 64;      \
      b[(NH) * 4 + nf * 2 + 0] = lds_frag(p_ + g0);                   \
      b[(NH) * 4 + nf * 2 + 1] = lds_frag(p_ + g1);                   \
    }                                                                 \
  } while (0)

#define MMQ(MQ, NH, AF)                                               \
  do {                                                                \
    _Pragma("unroll") for (int mf = 0; mf < 4; ++mf)                  \
      _Pragma("unroll") for (int nf = 0; nf < 2; ++nf) {              \
        f32x4 t_ = acc[(MQ) * 4 + mf][(NH) * 2 + nf];                 \
        t_ = MFMA16x16(AF[mf * 2 + 0], b[(NH) * 4 + nf * 2 + 0], t_); \
        t_ = MFMA16x16(AF[mf * 2 + 1], b[(NH) * 4 + nf * 2 + 1], t_); \
        acc[(MQ) * 4 + mf][(NH) * 2 + nf] = t_;                       \
      }                                                               \
  } while (0)

#define STG_A(buf, R0, kt) \
  GLOAD16(baseA + (size_t)(R0) * lda + (size_t)(kt) * 64, ldsA + (buf) * 16384 + (R0) * 64)
#define STG_B(buf, R0, kt) \
  GLOAD16(baseB + (size_t)(R0) * ldb + (size_t)(kt) * 64, ldsB + (buf) * 16384 + (R0) * 64)

template <typename CT, bool WRITEV>
__global__ __launch_bounds__(512, 2) void gemm256_kernel(const u16* __restrict__ A,
    const u16* __restrict__ Bt, CT* __restrict__ C, u16* __restrict__ Vt,
    int K, int lda, int ldb, int ldc) {
  __shared__ __align__(16) u16 sA[2][16384];
  __shared__ __align__(16) u16 sB[2][16384];
  const int tid = threadIdx.x;
  const int lane = tid & 63, wid = tid >> 6;
  const int r15 = lane & 15, hi = lane >> 4;
  const int wm = wid >> 2, wn = wid & 3;

  // XCD-aware bijective swizzle (nwg % 8 == 0 for both launches)
  const int gx = gridDim.x, nwg = gx * gridDim.y;
  const int orig = blockIdx.y * gx + blockIdx.x;
  const int wg = (orig & 7) * (nwg >> 3) + (orig >> 3);
  const int n0 = (wg % gx) * 256;
  const int m0 = (wg / gx) * 256;

  const int NT = K >> 6;       // 64-wide k tiles (even)
  const int NITER = NT >> 1;

  // staging: thread stages 1 granule (16B) per 64-row chunk
  const int rc = tid >> 3;                         // row within chunk
  const int cg = (tid & 7) ^ (rc & 7);             // logical source granule
  const u16* baseA = A + (size_t)(m0 + rc) * lda + cg * 8;
  const u16* baseB = Bt + (size_t)(n0 + rc) * ldb + cg * 8;
  u16* ldsA = &sA[0][0] + rc * 64 + (tid & 7) * 8; // linear physical dest
  u16* ldsB = &sB[0][0] + rc * 64 + (tid & 7) * 8;

  // per-thread-constant read swizzle: row&7 == r15&7 for all fragment rows
  const int sw = r15 & 7;
  const int g0 = (hi ^ sw) * 8;        // kstep 0 granule offset (u16 units)
  const int g1 = ((4 + hi) ^ sw) * 8;  // kstep 1
  const int awrow = wm * 128 + r15;
  const int bwrow = wn * 64 + r15;
  const u16* sA0 = &sA[0][0]; const u16* sA1 = &sA[1][0];
  const u16* sB0 = &sB[0][0]; const u16* sB1 = &sB[1][0];

  f32x4 acc[8][4] = {};
  bf16x8 aE[8], aO[8], b[8];

  // ---- prologue: T0 -> buf0 (8 chunks), T1 -> buf1 (6 of 8 chunks) ----
  STG_A(0, 0, 0); STG_A(0, 64, 0); STG_A(0, 128, 0); STG_A(0, 192, 0);
  STG_B(0, 0, 0); STG_B(0, 64, 0); STG_B(0, 128, 0); STG_B(0, 192, 0);
  STG_A(1, 0, 1); STG_A(1, 128, 1);
  STG_B(1, 0, 1); STG_B(1, 64, 1); STG_B(1, 128, 1); STG_B(1, 192, 1);
  asm volatile("s_waitcnt vmcnt(6)" ::: "memory");
  __builtin_amdgcn_sched_barrier(0);
  __builtin_amdgcn_s_barrier();
  // pre-read T0.A0 + T0.B01 (drained at P1's lgkmcnt(0))
  RD_A(sA0, 0, aE); RD_BH(sB0, 0);

  int kb = 0;
  auto iter = [&](auto lastc) {
    constexpr bool L = decltype(lastc)::value;
    const int kO = kb + 1, k2 = kb + 2, k3 = kb + 3;
    // P1: MM(0,0)=aE*b01; window: T0.B23; stage T1.A64/A192 (always)
    PH_BEGIN();
    RD_BH(sB0, 1);
    MMQ(0, 0, aE);
    PH_END();
    STG_A(1, 64, kO); STG_A(1, 192, kO);
    // P2: MM(0,1)=aE*b23; window: T0.A1 -> aO; stage T2.A0/A128
    PH_BEGIN();
    RD_A(sA0, 1, aO);
    MMQ(0, 1, aE);
    PH_END();
    if constexpr (!L) { STG_A(0, 0, k2); STG_A(0, 128, k2); }
    // P3: MM(1,0)=aO*b01; no window reads; stage T2.B0/B64; GATE buf1
    PH_BEGIN();
    MMQ(1, 0, aO);
    PH_END();
    if constexpr (!L) { STG_B(0, 0, k2); STG_B(0, 64, k2); GATE4(); }
    else              { GATE0(); }
    // P4: MM(1,1)=aO*b23; window: T1.A0 -> aE, T1.B01; stage T2.B128/B192
    PH_BEGIN();
    RD_A(sA1, 0, aE); RD_BH(sB1, 0);
    MMQ(1, 1, aO);
    PH_END();
    if constexpr (!L) { STG_B(0, 128, k2); STG_B(0, 192, k2); }
    // P5: MM(0,0)=aE*b01 (T1); window: T1.B23; stage T2.A64/A192
    PH_BEGIN();
    RD_BH(sB1, 1);
    MMQ(0, 0, aE);
    PH_END();
    if constexpr (!L) { STG_A(0, 64, k2); STG_A(0, 192, k2); }
    // P6: MM(0,1); window: T1.A1 -> aO; stage T3.A0/A128
    PH_BEGIN();
    RD_A(sA1, 1, aO);
    MMQ(0, 1, aE);
    PH_END();
    if constexpr (!L) { STG_A(1, 0, k3); STG_A(1, 128, k3); }
    // P7: MM(1,0); no window reads; stage T3.B0/B64; GATE buf0
    PH_BEGIN();
    MMQ(1, 0, aO);
    PH_END();
    if constexpr (!L) { STG_B(1, 0, k3); STG_B(1, 64, k3); GATE4(); }
    else              { GATE0(); }
    // P8: MM(1,1); window: T2.A0 -> aE, T2.B01; stage T3.B128/B192
    PH_BEGIN();
    if constexpr (!L) { RD_A(sA0, 0, aE); RD_BH(sB0, 0); }
    MMQ(1, 1, aO);
    PH_END();
    if constexpr (!L) { STG_B(1, 128, k3); STG_B(1, 192, k3); }
    kb += 2;
  };
  for (int i = 0; i < NITER - 1; ++i) iter(FalseT{});
  iter(TrueT{});

  // ---- epilogue ----
  if constexpr (WRITEV) {
    if (n0 >= 2 * kDM) {  // V third: write transposed+permuted into Vt
      const int hswap = ((hi & 1) << 1) | (hi >> 1);  // bits2<->3 of (s&15), /4
#pragma unroll
      for (int im = 0; im < 8; ++im) {
        const int m_base = m0 + wm * 128 + im * 16;   // 16-aligned
        const int bq = m_base >> 11;                  // batch
        const int sp = (m_base & (kS - 1)) + hswap * 4;
#pragma unroll
        for (int in = 0; in < 4; ++in) {
          const int c = n0 - 2 * kDM + wn * 64 + in * 16 + r15;
          const int hh = c >> 7, dd = c & 127;
          u16* dst = Vt + ((size_t)((bq * kH + hh) * kDK + dd)) * kS + sp;
          ushort4 pk;
          pk.x = f2bf(acc[im][in][0]); pk.y = f2bf(acc[im][in][1]);
          pk.z = f2bf(acc[im][in][2]); pk.w = f2bf(acc[im][in][3]);
          *reinterpret_cast<ushort4*>(dst) = pk;      // one 8B store
        }
      }
      return;
    }
  }
  const size_t crow0 = (size_t)(m0 + wm * 128 + hi * 4);
  const int col0 = n0 + wn * 64 + r15;
#pragma unroll
  for (int im = 0; im < 8; ++im)
#pragma unroll
    for (int in = 0; in < 4; ++in)
#pragma unroll
      for (int r = 0; r < 4; ++r)
        cstore(&C[(crow0 + im * 16 + r) * ldc + col0 + in * 16], acc[im][in][r]);
}

// ------------- flash attention (R6/R9 structure): 4 waves x QBLK=32 ----
// K/V double-buffered in LDS (64KB, 2 blocks/CU); Q staged once via lds[1]
// then registers. Vt pre-permuted so each PV B-fragment is one ds_read_b128.
// NEW (T1): XCD-aware head grouping — remap the 1024 blocks so each XCD owns
// whole heads (16 q-blocks of a head land on ONE XCD's L2 instead of 8):
// lin = x+16y+256z; r=lin&7 (XCD), k=lin>>3; head = r*8+(k>>4); qb = k&15.
// Bijective (1024%8==0); launch order packs 4 complete heads/XCD/round.
__global__ __launch_bounds__(256, 2) void attn_kernel(const u16* __restrict__ qkv,
    const u16* __restrict__ vt, u16* __restrict__ attn_out) {
  __shared__ __align__(16) u16 lds[2][16384];
  const int tid = threadIdx.x;
  const int lane = tid & 63, wid = tid >> 6;
  const int l31 = lane & 31, hi5 = lane >> 5;

  // XCD-aware work remap (pure index permutation)
  const int lin = blockIdx.x + (blockIdx.y << 4) + (blockIdx.z << 8); // 0..1023
  const int xr = lin & 7, kk = lin >> 3;
  const int head_lin = xr * 8 + (kk >> 4);    // 0..63
  const int q0 = (kk & 15) * 128;
  const int b = head_lin >> 4, h = head_lin & 15;
  const int bh = head_lin;

  const int krow = tid >> 4, kg = tid & 15;
  const u16* kp = qkv + (size_t)(b * kS + krow) * kNQKV + kDM + h * kDK
                  + (size_t)((kg ^ (krow & 7)) * 8);
  const int vrow = tid >> 3, vg = tid & 7;
  const u16* vp = vt + (size_t)(bh * kDK + vrow) * kS + (size_t)((vg ^ (vrow & 7)) * 8);

  auto stage_kv = [&](u16* dst) {
#pragma unroll
    for (int i = 0; i < 4; ++i)
      GLOAD16(kp + (size_t)i * 16 * kNQKV, dst + (tid + 256 * i) * 8);
#pragma unroll
    for (int i = 0; i < 4; ++i)
      GLOAD16(vp + (size_t)i * 32 * kS, dst + 8192 + (tid + 256 * i) * 8);
    kp += (size_t)64 * kNQKV;
    vp += 64;
  };

#pragma unroll
  for (int i = 0; i < 8; ++i) {
    int row = (tid >> 4) + 16 * i;
    GLOAD16(qkv + (size_t)(b * kS + q0 + row) * kNQKV + h * kDK
                + (size_t)(((tid & 15) ^ (row & 7)) * 8),
            (u16*)lds[1] + (tid + 256 * i) * 8);
  }
  stage_kv(lds[0]);
  __syncthreads();

  bf16x8 qf[8];
  {
    const int qrow = wid * 32 + l31;
    const u16* qb = (const u16*)lds[1];
#pragma unroll
    for (int ds = 0; ds < 8; ++ds) {
      int slot = (ds * 2 + hi5) ^ (qrow & 7);
      qf[ds] = lds_frag(&qb[qrow * 128 + slot * 8]);
    }
  }
  __syncthreads();

  f32x16 o[4] = {};
  float mi = -1e30f, li = 0.f;
  int cur = 0;

  for (int t = 0; t < kS / 64; ++t) {
    if (t < kS / 64 - 1) stage_kv(lds[cur ^ 1]);

    const u16* Kb = (const u16*)lds[cur];
    const u16* Vb = Kb + 8192;

    f32x16 s0 = {}, s1 = {};
    const int kr = l31;
    __builtin_amdgcn_s_setprio(1);
#pragma unroll
    for (int ds = 0; ds < 8; ++ds) {
      int slot = ((ds * 2 + hi5) ^ (kr & 7)) * 8;
      bf16x8 k0 = lds_frag(&Kb[kr * 128 + slot]);
      bf16x8 k1 = lds_frag(&Kb[(32 + kr) * 128 + slot]);
      s0 = __builtin_amdgcn_mfma_f32_32x32x16_bf16(k0, qf[ds], s0, 0, 0, 0);
      s1 = __builtin_amdgcn_mfma_f32_32x32x16_bf16(k1, qf[ds], s1, 0, 0, 0);
    }
    __builtin_amdgcn_s_setprio(0);

    float mx = s0[0];
#pragma unroll
    for (int r = 1; r < 16; ++r) mx = fmaxf(mx, s0[r]);
#pragma unroll
    for (int r = 0; r < 16; ++r) mx = fmaxf(mx, s1[r]);
    mx = fmaxf(mx, __shfl_xor(mx, 32));
    float mc = mx * kE2;
    if (__any(mc > mi + 8.0f)) {
      float mn = fmaxf(mi, mc);
      float corr = exp2_fast(mi - mn);
      mi = mn;
      li *= corr;
#pragma unroll
      for (int r = 0; r < 16; ++r) {
        float c = __shfl(corr, (r & 3) + 8 * (r >> 2) + 4 * hi5);
        o[0][r] *= c; o[1][r] *= c; o[2][r] *= c; o[3][r] *= c;
      }
    }
    float p0[16], p1[16];
    float rs = 0.f;
#pragma unroll
    for (int r = 0; r < 16; ++r) { p0[r] = exp2_fast(s0[r] * kE2 - mi); rs += p0[r]; }
#pragma unroll
    for (int r = 0; r < 16; ++r) { p1[r] = exp2_fast(s1[r] * kE2 - mi); rs += p1[r]; }
    rs += __shfl_xor(rs, 32);
    li += rs;

    u16x8 pw0, pw1, pw2, pw3;
#pragma unroll
    for (int r = 0; r < 8; ++r) {
      pw0[r] = f2bf(p0[r]);
      pw1[r] = f2bf(p0[r + 8]);
      pw2[r] = f2bf(p1[r]);
      pw3[r] = f2bf(p1[r + 8]);
    }
    bf16x8 pa[4] = {__builtin_bit_cast(bf16x8, pw0), __builtin_bit_cast(bf16x8, pw1),
                    __builtin_bit_cast(bf16x8, pw2), __builtin_bit_cast(bf16x8, pw3)};

    __builtin_amdgcn_s_setprio(1);
#pragma unroll
    for (int dt = 0; dt < 4; ++dt) {
      const int row = dt * 32 + l31;
      const int rs8 = row & 7;
#pragma unroll
      for (int ks = 0; ks < 4; ++ks) {
        bf16x8 bv = lds_frag(&Vb[row * 64 + ((ks * 2 + hi5) ^ rs8) * 8]);
        o[dt] = __builtin_amdgcn_mfma_f32_32x32x16_bf16(pa[ks], bv, o[dt], 0, 0, 0);
      }
    }
    __builtin_amdgcn_s_setprio(0);

    __syncthreads();
    cur ^= 1;
  }

  float rli = 1.0f / li;
  const size_t obase = (size_t)(b * kS + q0 + wid * 32) * kDM + h * kDK + l31;
#pragma unroll
  for (int r = 0; r < 16; ++r) {
    int ql = (r & 3) + 8 * (r >> 2) + 4 * hi5;
    float w = __shfl(rli, ql);
#pragma unroll
    for (int dt = 0; dt < 4; ++dt)
      attn_out[obase + (size_t)ql * kDM + dt * 32] = f2bf(o[dt][r] * w);
  }
}

// ---------------------------------------------------------------------------
extern "C" void kernel_launch(void* const* d_in, const int* in_sizes, int n_in,
                              void* d_out, int out_size, void* d_ws, size_t ws_size,
                              hipStream_t stream) {
  (void)in_sizes; (void)n_in; (void)out_size; (void)ws_size;
  const float* x  = (const float*)d_in[0];
  const float* wq = (const float*)d_in[1];
  const float* wk = (const float*)d_in[2];
  const float* wv = (const float*)d_in[3];
  const float* wo = (const float*)d_in[4];

  char* p = (char*)d_ws;
  u16* xb   = (u16*)p; p += (size_t)kM * kDM * 2;
  u16* wtc  = (u16*)p; p += (size_t)kNQKV * kDM * 2;
  u16* wot  = (u16*)p; p += (size_t)kDM * kDM * 2;
  u16* qkvb = (u16*)p; p += (size_t)kM * kNQKV * 2;
  u16* vtb  = (u16*)p; p += (size_t)kB * kH * kDK * kS * 2;
  u16* aob  = xb;  // reuse: x_bf16 dead after QKV gemm

  int n4 = kM * kDM / 4;
  cast_x_kernel<<<(n4 + 255) / 256, 256, 0, stream>>>(x, xb, n4);
  transpose_w_kernel<<<dim3(kDM / 32, kDM / 32, 4), dim3(32, 8), 0, stream>>>(
      wq, wk, wv, wo, wtc, wot);
  gemm256_kernel<u16, true><<<dim3(kNQKV / 256, kM / 256), 512, 0, stream>>>(
      xb, wtc, qkvb, vtb, kDM, kDM, kDM, kNQKV);
  attn_kernel<<<dim3(kS / 128, kH, kB), 256, 0, stream>>>(qkvb, vtb, aob);
  gemm256_kernel<float, false><<<dim3(kDM / 256, kM / 256), 512, 0, stream>>>(
      aob, wot, (float*)d_out, nullptr, kDM, kDM, kDM, kDM);
}

// Round 16
// 422.933 us; speedup vs baseline: 1.9448x; 1.0070x over previous
//
#include <hip/hip_runtime.h>
#include <hip/hip_bf16.h>

typedef __attribute__((ext_vector_type(8))) __bf16 bf16x8;
typedef __attribute__((ext_vector_type(4))) float f32x4;
typedef __attribute__((ext_vector_type(16))) float f32x16;
typedef __attribute__((ext_vector_type(8))) unsigned short u16x8;
typedef unsigned short u16;

#define DEVINL static __device__ __forceinline__

namespace {
constexpr int kB = 4;
constexpr int kS = 2048;
constexpr int kDM = 2048;
constexpr int kH = 16;
constexpr int kDK = 128;
constexpr int kM = kB * kS;        // 8192
constexpr int kNQKV = 3 * kDM;     // 6144
constexpr float kE2 = 0.08838834764831845f * 1.44269504088896f; // scale*log2(e)
}

DEVINL u16 f2bf(float f) {
  __hip_bfloat16 h = __float2bfloat16(f);
  return __builtin_bit_cast(u16, h);
}

#if __has_builtin(__builtin_amdgcn_exp2f)
DEVINL float exp2_fast(float x) { return __builtin_amdgcn_exp2f(x); }
#else
DEVINL float exp2_fast(float x) { return exp2f(x); }
#endif

#define GLOAD16(gp, lp) \
  __builtin_amdgcn_global_load_lds((const __attribute__((address_space(1))) void*)(gp), \
                                   (__attribute__((address_space(3))) void*)(lp), 16, 0, 0)

DEVINL bf16x8 lds_frag(const u16* p) { return *reinterpret_cast<const bf16x8*>(p); }

DEVINL f32x4 MFMA16x16(bf16x8 a, bf16x8 b, f32x4 c) {
  return __builtin_amdgcn_mfma_f32_16x16x32_bf16(a, b, c, 0, 0, 0);
}

struct TrueT { static constexpr bool value = true; };
struct FalseT { static constexpr bool value = false; };

// ---- fused prep: z<4 -> transpose+cast W_z; z>=4 -> cast x (fp32->bf16) ----
// Both phases memory-bound; fusing removes one launch gap and co-schedules
// the LDS-bound transpose blocks with the pure-streaming cast blocks.
__global__ __launch_bounds__(256) void prep_kernel(const float* __restrict__ x,
    const float* __restrict__ w0, const float* __restrict__ w1,
    const float* __restrict__ w2, const float* __restrict__ w3,
    u16* __restrict__ xb, u16* __restrict__ wtcat, u16* __restrict__ wot) {
  const int tx = threadIdx.x, ty = threadIdx.y;
  if (blockIdx.z >= 4) {
    // x cast: 16384 blocks x 256 threads x 1 float4 == kM*kDM exactly
    int blk = blockIdx.x + (blockIdx.y << 6) + ((blockIdx.z - 4) << 12);
    int i = blk * 256 + ty * 32 + tx;
    float4 v = reinterpret_cast<const float4*>(x)[i];
    ushort4 r;
    r.x = f2bf(v.x); r.y = f2bf(v.y); r.z = f2bf(v.z); r.w = f2bf(v.w);
    reinterpret_cast<ushort4*>(xb)[i] = r;
    return;
  }
  const float* src = (blockIdx.z == 0) ? w0 : (blockIdx.z == 1) ? w1
                    : (blockIdx.z == 2) ? w2 : w3;
  u16* dst = (blockIdx.z < 3) ? (wtcat + (size_t)blockIdx.z * kDM * kDM) : wot;
  __shared__ float tile[32][33];
  int n0 = blockIdx.x * 32, k0 = blockIdx.y * 32;
#pragma unroll
  for (int i = 0; i < 4; ++i)
    tile[ty + i * 8][tx] = src[(size_t)(k0 + ty + i * 8) * kDM + n0 + tx];
  __syncthreads();
#pragma unroll
  for (int i = 0; i < 4; ++i)
    dst[(size_t)(n0 + ty + i * 8) * kDM + k0 + tx] = f2bf(tile[tx][ty + i * 8]);
}

// ===================== 256x256 8-phase GEMM (Bt layout), 16x16x32 MFMA ======
// Single barrier per phase (R9). Stage slotting R5; gates vmcnt(4) at P3/P7.
DEVINL void cstore(float* p, float v) { *p = v; }
DEVINL void cstore(u16* p, float v) { *p = f2bf(v); }

#define PH_BEGIN()                                     \
  __builtin_amdgcn_sched_barrier(0);                   \
  __builtin_amdgcn_s_barrier();                        \
  asm volatile("s_waitcnt lgkmcnt(0)" ::: "memory");   \
  __builtin_amdgcn_sched_barrier(0);                   \
  __builtin_amdgcn_s_setprio(1)

#define PH_END()                                       \
  __builtin_amdgcn_s_setprio(0);                       \
  __builtin_amdgcn_sched_barrier(0)

#define GATE4() \
  asm volatile("s_waitcnt vmcnt(4)" ::: "memory");     \
  __builtin_amdgcn_sched_barrier(0)

#define GATE0() \
  asm volatile("s_waitcnt vmcnt(0)" ::: "memory");     \
  __builtin_amdgcn_sched_barrier(0)

// read A-half MQ of tile buffer SB into DST[0..7]
#define RD_A(SB, MQ, DST)                                             \
  do {                                                                \
    _Pragma("unroll") for (int mf = 0; mf < 4; ++mf) {                \
      const u16* p_ = (SB) + (awrow + (MQ) * 64 + mf * 16) * 64;      \
      DST[mf * 2 + 0] = lds_frag(p_ + g0);                            \
      DST[mf * 2 + 1] = lds_frag(p_ + g1);                            \
    }                                                                 \
  } while (0)

// read B-half NH of tile buffer SB into b[NH*4 .. NH*4+3]
#define RD_BH(SB, NH)                                                 \
  do {                                                                \
    _Pragma("unroll") for (int nf = 0; nf < 2; ++nf) {                \
      const u16* p_ = (SB) + (bwrow + (NH) * 32 + nf * 16) * 64;      \
      b[(NH) * 4 + nf * 2 + 0] = lds_frag(p_ + g0);                   \
      b[(NH) * 4 + nf * 2 + 1] = lds_frag(p_ + g1);                   \
    }                                                                 \
  } while (0)

#define MMQ(MQ, NH, AF)                                               \
  do {                                                                \
    _Pragma("unroll") for (int mf = 0; mf < 4; ++mf)                  \
      _Pragma("unroll") for (int nf = 0; nf < 2; ++nf) {              \
        f32x4 t_ = acc[(MQ) * 4 + mf][(NH) * 2 + nf];                 \
        t_ = MFMA16x16(AF[mf * 2 + 0], b[(NH) * 4 + nf * 2 + 0], t_); \
        t_ = MFMA16x16(AF[mf * 2 + 1], b[(NH) * 4 + nf * 2 + 1], t_); \
        acc[(MQ) * 4 + mf][(NH) * 2 + nf] = t_;                       \
      }                                                               \
  } while (0)

#define STG_A(buf, R0, kt) \
  GLOAD16(baseA + (size_t)(R0) * lda + (size_t)(kt) * 64, ldsA + (buf) * 16384 + (R0) * 64)
#define STG_B(buf, R0, kt) \
  GLOAD16(baseB + (size_t)(R0) * ldb + (size_t)(kt) * 64, ldsB + (buf) * 16384 + (R0) * 64)

template <typename CT, bool WRITEV>
__global__ __launch_bounds__(512, 2) void gemm256_kernel(const u16* __restrict__ A,
    const u16* __restrict__ Bt, CT* __restrict__ C, u16* __restrict__ Vt,
    int K, int lda, int ldb, int ldc) {
  __shared__ __align__(16) u16 sA[2][16384];
  __shared__ __align__(16) u16 sB[2][16384];
  const int tid = threadIdx.x;
  const int lane = tid & 63, wid = tid >> 6;
  const int r15 = lane & 15, hi = lane >> 4;
  const int wm = wid >> 2, wn = wid & 3;

  // XCD-aware bijective swizzle (nwg % 8 == 0 for both launches)
  const int gx = gridDim.x, nwg = gx * gridDim.y;
  const int orig = blockIdx.y * gx + blockIdx.x;
  const int wg = (orig & 7) * (nwg >> 3) + (orig >> 3);
  const int n0 = (wg % gx) * 256;
  const int m0 = (wg / gx) * 256;

  const int NT = K >> 6;       // 64-wide k tiles (even)
  const int NITER = NT >> 1;

  // staging: thread stages 1 granule (16B) per 64-row chunk
  const int rc = tid >> 3;                         // row within chunk
  const int cg = (tid & 7) ^ (rc & 7);             // logical source granule
  const u16* baseA = A + (size_t)(m0 + rc) * lda + cg * 8;
  const u16* baseB = Bt + (size_t)(n0 + rc) * ldb + cg * 8;
  u16* ldsA = &sA[0][0] + rc * 64 + (tid & 7) * 8; // linear physical dest
  u16* ldsB = &sB[0][0] + rc * 64 + (tid & 7) * 8;

  // per-thread-constant read swizzle: row&7 == r15&7 for all fragment rows
  const int sw = r15 & 7;
  const int g0 = (hi ^ sw) * 8;        // kstep 0 granule offset (u16 units)
  const int g1 = ((4 + hi) ^ sw) * 8;  // kstep 1
  const int awrow = wm * 128 + r15;
  const int bwrow = wn * 64 + r15;
  const u16* sA0 = &sA[0][0]; const u16* sA1 = &sA[1][0];
  const u16* sB0 = &sB[0][0]; const u16* sB1 = &sB[1][0];

  f32x4 acc[8][4] = {};
  bf16x8 aE[8], aO[8], b[8];

  // ---- prologue: T0 -> buf0 (8 chunks), T1 -> buf1 (6 of 8 chunks) ----
  STG_A(0, 0, 0); STG_A(0, 64, 0); STG_A(0, 128, 0); STG_A(0, 192, 0);
  STG_B(0, 0, 0); STG_B(0, 64, 0); STG_B(0, 128, 0); STG_B(0, 192, 0);
  STG_A(1, 0, 1); STG_A(1, 128, 1);
  STG_B(1, 0, 1); STG_B(1, 64, 1); STG_B(1, 128, 1); STG_B(1, 192, 1);
  asm volatile("s_waitcnt vmcnt(6)" ::: "memory");
  __builtin_amdgcn_sched_barrier(0);
  __builtin_amdgcn_s_barrier();
  // pre-read T0.A0 + T0.B01 (drained at P1's lgkmcnt(0))
  RD_A(sA0, 0, aE); RD_BH(sB0, 0);

  int kb = 0;
  auto iter = [&](auto lastc) {
    constexpr bool L = decltype(lastc)::value;
    const int kO = kb + 1, k2 = kb + 2, k3 = kb + 3;
    // P1: MM(0,0)=aE*b01; window: T0.B23; stage T1.A64/A192 (always)
    PH_BEGIN();
    RD_BH(sB0, 1);
    MMQ(0, 0, aE);
    PH_END();
    STG_A(1, 64, kO); STG_A(1, 192, kO);
    // P2: MM(0,1)=aE*b23; window: T0.A1 -> aO; stage T2.A0/A128
    PH_BEGIN();
    RD_A(sA0, 1, aO);
    MMQ(0, 1, aE);
    PH_END();
    if constexpr (!L) { STG_A(0, 0, k2); STG_A(0, 128, k2); }
    // P3: MM(1,0)=aO*b01; no window reads; stage T2.B0/B64; GATE buf1
    PH_BEGIN();
    MMQ(1, 0, aO);
    PH_END();
    if constexpr (!L) { STG_B(0, 0, k2); STG_B(0, 64, k2); GATE4(); }
    else              { GATE0(); }
    // P4: MM(1,1)=aO*b23; window: T1.A0 -> aE, T1.B01; stage T2.B128/B192
    PH_BEGIN();
    RD_A(sA1, 0, aE); RD_BH(sB1, 0);
    MMQ(1, 1, aO);
    PH_END();
    if constexpr (!L) { STG_B(0, 128, k2); STG_B(0, 192, k2); }
    // P5: MM(0,0)=aE*b01 (T1); window: T1.B23; stage T2.A64/A192
    PH_BEGIN();
    RD_BH(sB1, 1);
    MMQ(0, 0, aE);
    PH_END();
    if constexpr (!L) { STG_A(0, 64, k2); STG_A(0, 192, k2); }
    // P6: MM(0,1); window: T1.A1 -> aO; stage T3.A0/A128
    PH_BEGIN();
    RD_A(sA1, 1, aO);
    MMQ(0, 1, aE);
    PH_END();
    if constexpr (!L) { STG_A(1, 0, k3); STG_A(1, 128, k3); }
    // P7: MM(1,0); no window reads; stage T3.B0/B64; GATE buf0
    PH_BEGIN();
    MMQ(1, 0, aO);
    PH_END();
    if constexpr (!L) { STG_B(1, 0, k3); STG_B(1, 64, k3); GATE4(); }
    else              { GATE0(); }
    // P8: MM(1,1); window: T2.A0 -> aE, T2.B01; stage T3.B128/B192
    PH_BEGIN();
    if constexpr (!L) { RD_A(sA0, 0, aE); RD_BH(sB0, 0); }
    MMQ(1, 1, aO);
    PH_END();
    if constexpr (!L) { STG_B(1, 128, k3); STG_B(1, 192, k3); }
    kb += 2;
  };
  for (int i = 0; i < NITER - 1; ++i) iter(FalseT{});
  iter(TrueT{});

  // ---- epilogue ----
  if constexpr (WRITEV) {
    if (n0 >= 2 * kDM) {  // V third: write transposed+permuted into Vt
      const int hswap = ((hi & 1) << 1) | (hi >> 1);  // bits2<->3 of (s&15), /4
#pragma unroll
      for (int im = 0; im < 8; ++im) {
        const int m_base = m0 + wm * 128 + im * 16;   // 16-aligned
        const int bq = m_base >> 11;                  // batch
        const int sp = (m_base & (kS - 1)) + hswap * 4;
#pragma unroll
        for (int in = 0; in < 4; ++in) {
          const int c = n0 - 2 * kDM + wn * 64 + in * 16 + r15;
          const int hh = c >> 7, dd = c & 127;
          u16* dst = Vt + ((size_t)((bq * kH + hh) * kDK + dd)) * kS + sp;
          ushort4 pk;
          pk.x = f2bf(acc[im][in][0]); pk.y = f2bf(acc[im][in][1]);
          pk.z = f2bf(acc[im][in][2]); pk.w = f2bf(acc[im][in][3]);
          *reinterpret_cast<ushort4*>(dst) = pk;      // one 8B store
        }
      }
      return;
    }
  }
  const size_t crow0 = (size_t)(m0 + wm * 128 + hi * 4);
  const int col0 = n0 + wn * 64 + r15;
#pragma unroll
  for (int im = 0; im < 8; ++im)
#pragma unroll
    for (int in = 0; in < 4; ++in)
#pragma unroll
      for (int r = 0; r < 4; ++r)
        cstore(&C[(crow0 + im * 16 + r) * ldc + col0 + in * 16], acc[im][in][r]);
}

// ------------- flash attention (R6/R9 structure): 4 waves x QBLK=32 ----
// K/V double-buffered in LDS (64KB, 2 blocks/CU); Q staged once via lds[1]
// then registers. Vt pre-permuted so each PV B-fragment is one ds_read_b128.
// T1 (R15, +10us): XCD-aware head grouping — each XCD owns whole heads:
// lin = x+16y+256z; r=lin&7 (XCD), k=lin>>3; head = r*8+(k>>4); qb = k&15.
__global__ __launch_bounds__(256, 2) void attn_kernel(const u16* __restrict__ qkv,
    const u16* __restrict__ vt, u16* __restrict__ attn_out) {
  __shared__ __align__(16) u16 lds[2][16384];
  const int tid = threadIdx.x;
  const int lane = tid & 63, wid = tid >> 6;
  const int l31 = lane & 31, hi5 = lane >> 5;

  // XCD-aware work remap (pure index permutation)
  const int lin = blockIdx.x + (blockIdx.y << 4) + (blockIdx.z << 8); // 0..1023
  const int xr = lin & 7, kk = lin >> 3;
  const int head_lin = xr * 8 + (kk >> 4);    // 0..63
  const int q0 = (kk & 15) * 128;
  const int b = head_lin >> 4, h = head_lin & 15;
  const int bh = head_lin;

  const int krow = tid >> 4, kg = tid & 15;
  const u16* kp = qkv + (size_t)(b * kS + krow) * kNQKV + kDM + h * kDK
                  + (size_t)((kg ^ (krow & 7)) * 8);
  const int vrow = tid >> 3, vg = tid & 7;
  const u16* vp = vt + (size_t)(bh * kDK + vrow) * kS + (size_t)((vg ^ (vrow & 7)) * 8);

  auto stage_kv = [&](u16* dst) {
#pragma unroll
    for (int i = 0; i < 4; ++i)
      GLOAD16(kp + (size_t)i * 16 * kNQKV, dst + (tid + 256 * i) * 8);
#pragma unroll
    for (int i = 0; i < 4; ++i)
      GLOAD16(vp + (size_t)i * 32 * kS, dst + 8192 + (tid + 256 * i) * 8);
    kp += (size_t)64 * kNQKV;
    vp += 64;
  };

#pragma unroll
  for (int i = 0; i < 8; ++i) {
    int row = (tid >> 4) + 16 * i;
    GLOAD16(qkv + (size_t)(b * kS + q0 + row) * kNQKV + h * kDK
                + (size_t)(((tid & 15) ^ (row & 7)) * 8),
            (u16*)lds[1] + (tid + 256 * i) * 8);
  }
  stage_kv(lds[0]);
  __syncthreads();

  bf16x8 qf[8];
  {
    const int qrow = wid * 32 + l31;
    const u16* qb = (const u16*)lds[1];
#pragma unroll
    for (int ds = 0; ds < 8; ++ds) {
      int slot = (ds * 2 + hi5) ^ (qrow & 7);
      qf[ds] = lds_frag(&qb[qrow * 128 + slot * 8]);
    }
  }
  __syncthreads();

  f32x16 o[4] = {};
  float mi = -1e30f, li = 0.f;
  int cur = 0;

  for (int t = 0; t < kS / 64; ++t) {
    if (t < kS / 64 - 1) stage_kv(lds[cur ^ 1]);

    const u16* Kb = (const u16*)lds[cur];
    const u16* Vb = Kb + 8192;

    f32x16 s0 = {}, s1 = {};
    const int kr = l31;
    __builtin_amdgcn_s_setprio(1);
#pragma unroll
    for (int ds = 0; ds < 8; ++ds) {
      int slot = ((ds * 2 + hi5) ^ (kr & 7)) * 8;
      bf16x8 k0 = lds_frag(&Kb[kr * 128 + slot]);
      bf16x8 k1 = lds_frag(&Kb[(32 + kr) * 128 + slot]);
      s0 = __builtin_amdgcn_mfma_f32_32x32x16_bf16(k0, qf[ds], s0, 0, 0, 0);
      s1 = __builtin_amdgcn_mfma_f32_32x32x16_bf16(k1, qf[ds], s1, 0, 0, 0);
    }
    __builtin_amdgcn_s_setprio(0);

    float mx = s0[0];
#pragma unroll
    for (int r = 1; r < 16; ++r) mx = fmaxf(mx, s0[r]);
#pragma unroll
    for (int r = 0; r < 16; ++r) mx = fmaxf(mx, s1[r]);
    mx = fmaxf(mx, __shfl_xor(mx, 32));
    float mc = mx * kE2;
    if (__any(mc > mi + 8.0f)) {
      float mn = fmaxf(mi, mc);
      float corr = exp2_fast(mi - mn);
      mi = mn;
      li *= corr;
#pragma unroll
      for (int r = 0; r < 16; ++r) {
        float c = __shfl(corr, (r & 3) + 8 * (r >> 2) + 4 * hi5);
        o[0][r] *= c; o[1][r] *= c; o[2][r] *= c; o[3][r] *= c;
      }
    }
    float p0[16], p1[16];
    float rs = 0.f;
#pragma unroll
    for (int r = 0; r < 16; ++r) { p0[r] = exp2_fast(s0[r] * kE2 - mi); rs += p0[r]; }
#pragma unroll
    for (int r = 0; r < 16; ++r) { p1[r] = exp2_fast(s1[r] * kE2 - mi); rs += p1[r]; }
    rs += __shfl_xor(rs, 32);
    li += rs;

    u16x8 pw0, pw1, pw2, pw3;
#pragma unroll
    for (int r = 0; r < 8; ++r) {
      pw0[r] = f2bf(p0[r]);
      pw1[r] = f2bf(p0[r + 8]);
      pw2[r] = f2bf(p1[r]);
      pw3[r] = f2bf(p1[r + 8]);
    }
    bf16x8 pa[4] = {__builtin_bit_cast(bf16x8, pw0), __builtin_bit_cast(bf16x8, pw1),
                    __builtin_bit_cast(bf16x8, pw2), __builtin_bit_cast(bf16x8, pw3)};

    __builtin_amdgcn_s_setprio(1);
#pragma unroll
    for (int dt = 0; dt < 4; ++dt) {
      const int row = dt * 32 + l31;
      const int rs8 = row & 7;
#pragma unroll
      for (int ks = 0; ks < 4; ++ks) {
        bf16x8 bv = lds_frag(&Vb[row * 64 + ((ks * 2 + hi5) ^ rs8) * 8]);
        o[dt] = __builtin_amdgcn_mfma_f32_32x32x16_bf16(pa[ks], bv, o[dt], 0, 0, 0);
      }
    }
    __builtin_amdgcn_s_setprio(0);

    __syncthreads();
    cur ^= 1;
  }

  float rli = 1.0f / li;
  const size_t obase = (size_t)(b * kS + q0 + wid * 32) * kDM + h * kDK + l31;
#pragma unroll
  for (int r = 0; r < 16; ++r) {
    int ql = (r & 3) + 8 * (r >> 2) + 4 * hi5;
    float w = __shfl(rli, ql);
#pragma unroll
    for (int dt = 0; dt < 4; ++dt)
      attn_out[obase + (size_t)ql * kDM + dt * 32] = f2bf(o[dt][r] * w);
  }
}

// ---------------------------------------------------------------------------
extern "C" void kernel_launch(void* const* d_in, const int* in_sizes, int n_in,
                              void* d_out, int out_size, void* d_ws, size_t ws_size,
                              hipStream_t stream) {
  (void)in_sizes; (void)n_in; (void)out_size; (void)ws_size;
  const float* x  = (const float*)d_in[0];
  const float* wq = (const float*)d_in[1];
  const float* wk = (const float*)d_in[2];
  const float* wv = (const float*)d_in[3];
  const float* wo = (const float*)d_in[4];

  char* p = (char*)d_ws;
  u16* xb   = (u16*)p; p += (size_t)kM * kDM * 2;
  u16* wtc  = (u16*)p; p += (size_t)kNQKV * kDM * 2;
  u16* wot  = (u16*)p; p += (size_t)kDM * kDM * 2;
  u16* qkvb = (u16*)p; p += (size_t)kM * kNQKV * 2;
  u16* vtb  = (u16*)p; p += (size_t)kB * kH * kDK * kS * 2;
  u16* aob  = xb;  // reuse: x_bf16 dead after QKV gemm

  prep_kernel<<<dim3(kDM / 32, kDM / 32, 8), dim3(32, 8), 0, stream>>>(
      x, wq, wk, wv, wo, xb, wtc, wot);
  gemm256_kernel<u16, true><<<dim3(kNQKV / 256, kM / 256), 512, 0, stream>>>(
      xb, wtc, qkvb, vtb, kDM, kDM, kDM, kNQKV);
  attn_kernel<<<dim3(kS / 128, kH, kB), 256, 0, stream>>>(qkvb, vtb, aob);
  gemm256_kernel<float, false><<<dim3(kDM / 256, kM / 256), 512, 0, stream>>>(
      aob, wot, (float*)d_out, nullptr, kDM, kDM, kDM, kDM);
}